// Round 8
// baseline (1375.968 us; speedup 1.0000x reference)
//
#include <hip/hip_runtime.h>
#include <hip/hip_fp8.h>

// Problem constants
#define NB   2048   // batch
#define SEQ  168    // encoder steps
#define NF   7      // features
#define NH   128    // hidden
#define NP   96     // decoder steps
#define EROWS 8     // rows/block -> 256 blocks, enc+dec fused
#define DROWS 8
#define NTHR 512
#define KE   160    // enc A/B K: [x 0..6][pad 7][h 8..135][pad 136..159]
#define KD   256    // dec A/B K: [combine 0..127][prev_h 128..255]
#define HXS  168    // h16 row stride for enc MFMA-A tile
#define CTS  264    // cath row stride in h16
#define LS4  30     // s4 groups LDS-resident (s 0..119); tail 12 s4 in registers

typedef _Float16 h16;
typedef _Float16 h16x8 __attribute__((ext_vector_type(8)));
typedef float    f32x2 __attribute__((ext_vector_type(2)));
typedef float    f32x4 __attribute__((ext_vector_type(4)));
typedef unsigned int u32x4 __attribute__((ext_vector_type(4)));

// MFMA via the compiler builtin. Its A/B operands are AV-class (VGPR-or-AGPR)
// on gfx950, so PIN_A'd weight fragments are consumed directly from AGPRs —
// keeps the unified-RF residency (R3's anti-spill win) while the COMPILER owns
// operand constraints. (R6/R7's hand-written asm failed numerically only under
// the pipeline's register pressure; schedule analysis is clean — this swaps the
// one unverified component.)
__device__ __forceinline__ void mfma_b(f32x4& acc, h16x8 a, h16x8 b) {
  acc = __builtin_amdgcn_mfma_f32_16x16x32_f16(a, b, acc, 0, 0, 0);
}
#define PIN_A(x) asm volatile("" : "+a"(x))

__device__ __forceinline__ float sigm(float x) { return 1.f / (1.f + __expf(-x)); }
__device__ __forceinline__ float tanh_(float x) {
  float e = __expf(-2.f * fabsf(x));
  return copysignf((1.f - e) / (1.f + e), x);
}

template <bool HI>
__device__ __forceinline__ unsigned int pack2_fp8(float a, float b, unsigned int old) {
#if __has_builtin(__builtin_amdgcn_cvt_pk_fp8_f32)
  return (unsigned int)__builtin_amdgcn_cvt_pk_fp8_f32(a, b, (int)old, HI);
#else
  __hip_fp8_e4m3 qa(a), qb(b);
  unsigned int pair = (unsigned int)(*(unsigned char*)&qa) |
                      ((unsigned int)(*(unsigned char*)&qb) << 8);
  return HI ? ((old & 0x0000ffffu) | (pair << 16)) : ((old & 0xffff0000u) | pair);
#endif
}
template <bool HI>
__device__ __forceinline__ f32x2 unp2(unsigned int w) {
#if __has_builtin(__builtin_amdgcn_cvt_pk_f32_fp8)
  return __builtin_amdgcn_cvt_pk_f32_fp8(w, HI);
#else
  __hip_fp8_e4m3 a, b;
  constexpr unsigned int sh = HI ? 16 : 0;
  *(unsigned char*)&a = (w >> sh) & 0xff;
  *(unsigned char*)&b = (w >> (sh + 8)) & 0xff;
  f32x2 r; r.x = (float)a; r.y = (float)b; return r;
#endif
}

// -------- d_ws layout (bytes). --------
constexpr size_t WENC_OFF   = 0;         // h16[512][160]
constexpr size_t WDEC_OFF   = 163840;    // h16[512][256]
constexpr size_t WEFF_OFF   = 425984;    // h16[168][128]
constexpr size_t BEFF_OFF   = 468992;    // f32[168]
constexpr size_t WCOMB_OFF  = 469760;    // f32[128]
constexpr size_t BCONST_OFF = 470272;    // f32[1]
constexpr size_t BENC_OFF   = 470528;    // f32[512]
constexpr size_t BDEC_OFF   = 472576;    // f32[512]
constexpr size_t ENC2_OFF   = 31981568;  // u32[NB][3][128][4] hist tail (s4 30..41)
constexpr size_t HT_OFF     = 44564480;  // f32[NB*NH] final encoder h

// -------- fused-kernel dynamic-LDS layout (bytes) --------
constexpr int HIST_OFF   = 0;        // u32[8][30][128]  122880
constexpr int CATH_OFF   = 122880;   // h16[2][8][CTS]     8448 -> 131328
constexpr int ATTW_OFF   = 131328;   // f32[8][168]        5376 -> 136704
constexpr int WAT2_OFF   = 136704;   // h16[40][128]      10240 -> 146944
constexpr int D0_OFF     = 146944;   // f32[8][168]        5376 -> 152320
constexpr int OUTP_OFF   = 152320;   // f32[2][8][8] dbuf   512 -> 152832
constexpr int YH_OFF     = 152832;   // f32[64]             256 -> 153088
constexpr int OBUF_OFF   = 153088;   // f32[8][8] out ring  256 -> 153344
constexpr int DSMEM      = 153344;
// enc-phase alias (dead before dec phase uses these bytes): sh_hx over CATH/ATTW
constexpr int SHHX_OFF = 122880;     // h16[2][16][HXS] = 10752 (ends 133632)

// -------- setup: cast/pack weights + algebraic folds into ws --------
__global__ void setup_weights(const float* __restrict__ Wih_enc, const float* __restrict__ Whh_enc,
                              const float* __restrict__ Wih_dec, const float* __restrict__ Whh_dec,
                              const float* __restrict__ Watt, const float* __restrict__ batt,
                              const float* __restrict__ Wout, const float* __restrict__ bout,
                              const float* __restrict__ Wfin, const float* __restrict__ bfin,
                              const float* __restrict__ bihe, const float* __restrict__ bhhe,
                              const float* __restrict__ bihd, const float* __restrict__ bhhd,
                              char* __restrict__ ws) {
  int idx = blockIdx.x * blockDim.x + threadIdx.x;
  constexpr int A0 = 81920;            // enc W
  constexpr int A1 = A0 + 131072;      // dec W
  constexpr int A2 = A1 + 21504;       // Weff
  constexpr int A3 = A2 + 168;         // beff
  constexpr int A4 = A3 + 128;         // wcomb
  constexpr int A5 = A4 + 1;           // bconst
  constexpr int A6 = A5 + 512;         // biases
  if (idx < A0) {
    int n = idx / KE, k = idx % KE;
    float v = 0.f;
    if (k < NF) v = Wih_enc[n * NF + k];
    else if (k >= 8 && k < 136) v = Whh_enc[n * NH + (k - 8)];
    ((h16*)(ws + WENC_OFF))[idx] = (h16)v;
  } else if (idx < A1) {
    int i = idx - A0;
    int n = i / KD, k = i % KD;
    float v = (k < NH) ? Wih_dec[n * NH + k] : Whh_dec[n * NH + (k - NH)];
    ((h16*)(ws + WDEC_OFF))[i] = (h16)v;
  } else if (idx < A2) {
    int i = idx - A1;
    int s = i / NH, k = i % NH;
    float v = Watt[s * (NH + NF) + k];
    #pragma unroll
    for (int f = 0; f < NF; ++f)
      v += Watt[s * (NH + NF) + NH + f] * Wout[f * NH + k];
    ((h16*)(ws + WEFF_OFF))[i] = (h16)v;
  } else if (idx < A3) {
    int s = idx - A2;
    float v = batt[s];
    #pragma unroll
    for (int f = 0; f < NF; ++f)
      v += Watt[s * (NH + NF) + NH + f] * bout[f];
    ((float*)(ws + BEFF_OFF))[s] = v;
  } else if (idx < A4) {
    int k = idx - A3;
    float v = 0.f;
    #pragma unroll
    for (int f = 0; f < NF; ++f) v += Wfin[f] * Wout[f * NH + k];
    ((float*)(ws + WCOMB_OFF))[k] = v;
  } else if (idx < A5) {
    float v = bfin[0];
    #pragma unroll
    for (int f = 0; f < NF; ++f) v += bout[f] * Wfin[f];
    ((float*)(ws + BCONST_OFF))[0] = v;
  } else if (idx < A6) {
    int g = idx - A5;
    ((float*)(ws + BENC_OFF))[g] = bihe[g] + bhhe[g];
    ((float*)(ws + BDEC_OFF))[g] = bihd[g] + bhhd[g];
  }
}

// ================= fused encoder+decoder: 8 rows/block, 256 blocks =================
// Decoder: 2-group (rows 0-3 / 4-7) software pipeline — every barrier interval holds
// one MFMA-phase and one VALU-phase from different groups:
//   I1: D4(B@p-1) | D1(A@p)     I2: D1(B@p) | D3(A@p)     I3: D3(B@p) | D4(A@p)
__global__ __attribute__((amdgpu_flat_work_group_size(NTHR, NTHR), amdgpu_waves_per_eu(2, 2)))
void fused_kernel(const float* __restrict__ xb, const h16* __restrict__ w16enc,
                  const float* __restrict__ bencp, unsigned int* __restrict__ encw2,
                  float* __restrict__ hTg,
                  const float* __restrict__ Watt, const float* __restrict__ Wout,
                  const float* __restrict__ bout,
                  const h16* __restrict__ w16dec, const h16* __restrict__ weff,
                  const float* __restrict__ beffp, const float* __restrict__ wcombp,
                  const float* __restrict__ bconstp, const float* __restrict__ bdecp,
                  float* __restrict__ out) {
  extern __shared__ char smem[];
  unsigned int* hist = (unsigned int*)(smem + HIST_OFF);
  h16 (*sh_hx)[16][HXS] = (h16(*)[16][HXS])(smem + SHHX_OFF);
  h16*   sh_cath  = (h16*)(smem + CATH_OFF);
  float* sh_attw  = (float*)(smem + ATTW_OFF);
  h16*   sh_watt2 = (h16*)(smem + WAT2_OFF);
  float* sh_d0    = (float*)(smem + D0_OFF);
  float* sh_outp  = (float*)(smem + OUTP_OFF);   // [2][8][8]
  float* sh_yh    = (float*)(smem + YH_OFF);
  float* sh_obuf  = (float*)(smem + OBUF_OFF);

  const int t  = threadIdx.x;
  const int r0 = blockIdx.x * EROWS;

  const int w  = t >> 6;
  const int l  = t & 63;
  const int lq = l >> 4;
  const int ln = l & 15;
  const int hcol = w * 16 + ln;
  const int mrow = lq * 4;
  const bool act = (lq < 2);   // enc: rows mrow+reg = 0..7 real

  // xstash constants (enc)
  const int j  = t & 3;
  const int rf = t >> 2;
  const int xr = rf / NF;
  const int xf = rf - xr * NF;

  // ================== ENCODER PHASE ==================
  for (int i = t; i < 2 * 16 * HXS; i += NTHR) ((h16*)sh_hx)[i] = (h16)0.f;

  h16x8 bfE[4][5];
  float bE[4];
  #pragma unroll
  for (int g = 0; g < 4; ++g) {
    int n = g * 128 + hcol;
    bE[g] = bencp[n];
    #pragma unroll
    for (int kt = 0; kt < 5; ++kt) {
      bfE[g][kt] = *(const h16x8*)(w16enc + n * KE + kt * 32 + lq * 8);
      PIN_A(bfE[g][kt]);
    }
  }
  __syncthreads();
  if (t < EROWS * NF) {
    int r = t / NF, f = t - (t / NF) * NF;
    sh_hx[0][r][f] = (h16)xb[((size_t)(r0 + r) * SEQ + 0) * NF + f];
  }

  float creg[4] = {0.f, 0.f, 0.f, 0.f};
  float hstate[4] = {0.f, 0.f, 0.f, 0.f};
  float hprev[4] = {0.f, 0.f, 0.f, 0.f};
  unsigned int hpack[4] = {0u, 0u, 0u, 0u};
  float xstash = 0.f;

  __syncthreads();

  for (int s = 0; s < SEQ; ++s) {
    const int cur = s & 1;
    if ((s & 3) == 0 && t < EROWS * NF * 4) {
      int sx = s + 1 + j;
      xstash = (sx < SEQ) ? xb[((size_t)(r0 + xr) * SEQ + sx) * NF + xf] : 0.f;
    }

    f32x4 ac[4] = {{0.f,0.f,0.f,0.f},{0.f,0.f,0.f,0.f},{0.f,0.f,0.f,0.f},{0.f,0.f,0.f,0.f}};
    #pragma unroll
    for (int kt = 0; kt < 5; ++kt) {
      h16x8 af = *(const h16x8*)(&sh_hx[cur][ln][kt * 32 + lq * 8]);
      #pragma unroll
      for (int g = 0; g < 4; ++g)
        mfma_b(ac[g], af, bfE[g][kt]);
    }

    if (act) {
      #pragma unroll
      for (int reg = 0; reg < 4; ++reg) {
        float gi = sigm(ac[0][reg] + bE[0]);
        float gf = sigm(ac[1][reg] + bE[1]);
        float gg = tanh_(ac[2][reg] + bE[2]);
        float go = sigm(ac[3][reg] + bE[3]);
        float c = gf * creg[reg] + gi * gg;
        creg[reg] = c;
        float h = go * tanh_(c);
        hstate[reg] = h;
        sh_hx[cur ^ 1][mrow + reg][8 + hcol] = (h16)h;
        float hs = h * 16.f;
        if ((s & 1) == 0) hprev[reg] = hs;
        else if ((s & 3) == 1) hpack[reg] = pack2_fp8<false>(hprev[reg], hs, hpack[reg]);
        else                   hpack[reg] = pack2_fp8<true>(hprev[reg], hs, hpack[reg]);
      }
      if ((s & 3) == 3) {
        int s4 = s >> 2;
        if (s4 < LS4) {
          #pragma unroll
          for (int reg = 0; reg < 4; ++reg)
            hist[(size_t)(mrow + reg) * (LS4 * NH) + s4 * NH + hcol] = hpack[reg];
        } else {
          int q = s4 - LS4;
          #pragma unroll
          for (int reg = 0; reg < 4; ++reg)
            encw2[(((size_t)(r0 + mrow + reg) * 3 + (q >> 2)) * NH + hcol) * 4 + (q & 3)] = hpack[reg];
        }
      }
    }
    if (t < EROWS * NF * 4 && (s & 3) == j && s + 1 < SEQ)
      sh_hx[cur ^ 1][xr][xf] = (h16)xstash;
    __syncthreads();
  }

  // h_T to global (needed cross-lane for yh init)
  if (act) {
    #pragma unroll
    for (int reg = 0; reg < 4; ++reg)
      hTg[(size_t)(r0 + mrow + reg) * NH + hcol] = hstate[reg];
  }
  __syncthreads();

  // ================== DECODER PHASE ==================
  for (int i = t; i < 40 * NH; i += NTHR) sh_watt2[i] = weff[128 * NH + i];

  h16x8 bfD[3][8];
  float bD[3];
  #pragma unroll
  for (int g = 0; g < 3; ++g) {
    int n = g * 128 + hcol;
    bD[g] = bdecp[n];
    #pragma unroll
    for (int kt = 0; kt < 8; ++kt) {
      bfD[g][kt] = *(const h16x8*)(w16dec + n * KD + kt * 32 + lq * 8);
      PIN_A(bfD[g][kt]);
    }
  }
  h16x8 bfA[4];
  #pragma unroll
  for (int kt = 0; kt < 4; ++kt) {
    bfA[kt] = *(const h16x8*)(weff + hcol * NH + kt * 32 + lq * 8);
    PIN_A(bfA[kt]);
  }
  const float beffR = beffp[hcol];
  const int s2v = 128 + hcol;
  const float beff2 = (w < 3 && s2v < SEQ) ? beffp[s2v] : 0.f;
  const float wcombR = wcombp[hcol];
  const float bconstv = bconstp[0];

  // per-group cell state, both held in lq==0 lanes.
  float cregA[4], cregB[4];
  #pragma unroll
  for (int reg = 0; reg < 4; ++reg) {
    cregA[reg] = hstate[reg];
    cregB[reg] = __shfl(hstate[reg], 16 + ln);
  }
  // prev_h init into cath[0] (rows 0-7, by enc act lanes)
  if (act) {
    #pragma unroll
    for (int reg = 0; reg < 4; ++reg)
      sh_cath[0 * 8 * CTS + (mrow + reg) * CTS + 128 + hcol] = (h16)hstate[reg];
  }
  // yh[r][f] = h_T . W_out[f] + bout[f]
  if (t < DROWS * NF) {
    int r = t / NF, f = t - (t / NF) * NF;
    float a = bout[f];
    const float* wr = Wout + f * NH;
    const float* hp = hTg + (size_t)(r0 + r) * NH;
    #pragma unroll 8
    for (int k = 0; k < NH; k += 4) {
      float4 pv = *(const float4*)(hp + k);
      float4 wv = *(const float4*)(wr + k);
      a += pv.x * wv.x + pv.y * wv.y + pv.z * wv.z + pv.w * wv.w;
    }
    sh_yh[t] = a;
  }
  __syncthreads();
  // d0[r][s] = (y0[r] - yh[r]) . W_att_y[s]
  for (int i = t; i < DROWS * SEQ; i += NTHR) {
    int r = i / SEQ, s = i - (i / SEQ) * SEQ;
    float a = 0.f;
    #pragma unroll
    for (int f = 0; f < NF; ++f) {
      float y0f = xb[((size_t)(r0 + r) * SEQ + (SEQ - 1)) * NF + f];
      a += (y0f - sh_yh[r * NF + f]) * Watt[s * (NH + NF) + NH + f];
    }
    sh_d0[i] = a;
  }

  // D3 ownership: thread owns column dh for row dr of the active group
  const int dr = t >> 7;
  const int dh = t & 127;
  const unsigned int* hrowA = hist + (size_t)dr * (LS4 * NH) + dh;
  const unsigned int* hrowB = hist + (size_t)(dr + 4) * (LS4 * NH) + dh;
  const float* erowA = sh_attw + dr * SEQ;
  const float* erowB = sh_attw + (dr + 4) * SEQ;

  u32x4 tA[3], tB[3];
  {
    const u32x4* e2 = (const u32x4*)encw2;
    #pragma unroll
    for (int b = 0; b < 3; ++b) {
      tA[b] = e2[((size_t)(r0 + dr)     * 3 + b) * NH + dh];
      tB[b] = e2[((size_t)(r0 + dr + 4) * 3 + b) * NH + dh];
    }
  }
  __syncthreads();

  // ---- group-phase helpers ----
  // D1: logits for rows G*4..G*4+3. A-tile rows replicated (ln&3) -> C rows 0-3 real.
  auto D1g = [&](int G, int CA, bool p0) {
    const int arow = G * 4 + (ln & 3);
    h16x8 afA[4];
    #pragma unroll
    for (int kt = 0; kt < 4; ++kt)
      afA[kt] = *(const h16x8*)(sh_cath + CA * 8 * CTS + arow * CTS + 128 + kt * 32 + lq * 8);
    f32x4 acc = {0.f, 0.f, 0.f, 0.f};
    #pragma unroll
    for (int kt = 0; kt < 4; ++kt)
      mfma_b(acc, afA[kt], bfA[kt]);
    if (lq == 0) {
      #pragma unroll
      for (int reg = 0; reg < 4; ++reg) {
        int row = G * 4 + reg;
        float lg = acc[reg] + beffR;
        if (p0) lg += sh_d0[row * SEQ + hcol];
        lg = fminf(fmaxf(lg, -30.f), 30.f);
        sh_attw[row * SEQ + hcol] = __expf(lg);
      }
    }
    if (w < 3) {
      int srow = (s2v < SEQ ? s2v : SEQ - 1) - 128;
      f32x4 acc2 = {0.f, 0.f, 0.f, 0.f};
      #pragma unroll
      for (int kt = 0; kt < 4; ++kt) {
        h16x8 bf2 = *(const h16x8*)(sh_watt2 + srow * NH + kt * 32 + lq * 8);
        mfma_b(acc2, afA[kt], bf2);
      }
      if (s2v < SEQ && lq == 0) {
        #pragma unroll
        for (int reg = 0; reg < 4; ++reg) {
          int row = G * 4 + reg;
          float lg = acc2[reg] + beff2;
          if (p0) lg += sh_d0[row * SEQ + s2v];
          lg = fminf(fmaxf(lg, -30.f), 30.f);
          sh_attw[row * SEQ + s2v] = __expf(lg);
        }
      }
    }
  };

  // D3: combine for one group row per thread.
  auto D3g = [&](int G, int CA, const u32x4* treg, const unsigned int* hrow, const float* erow) {
    float d = erow[l] + erow[64 + l];
    if (l < SEQ - 128) d += erow[128 + l];
    #pragma unroll
    for (int k = 1; k < 64; k <<= 1) d += __shfl_xor(d, k);
    const float inv = 0.0625f / d;

    f32x2 av = {0.f, 0.f};
    #pragma unroll 6
    for (int s4 = 0; s4 < LS4; ++s4) {
      unsigned int ev = hrow[s4 * NH];
      float4 e4 = *(const float4*)(erow + s4 * 4);
      f32x2 w01 = {e4.x, e4.y}, w23 = {e4.z, e4.w};
      av = w01 * unp2<false>(ev) + av;
      av = w23 * unp2<true>(ev) + av;
    }
    #pragma unroll
    for (int b = 0; b < 3; ++b) {
      #pragma unroll
      for (int jj = 0; jj < 4; ++jj) {
        int s4 = LS4 + b * 4 + jj;
        unsigned int ev = treg[b][jj];
        float4 e4 = *(const float4*)(erow + s4 * 4);
        f32x2 w01 = {e4.x, e4.y}, w23 = {e4.z, e4.w};
        av = w01 * unp2<false>(ev) + av;
        av = w23 * unp2<true>(ev) + av;
      }
    }
    sh_cath[CA * 8 * CTS + (G * 4 + dr) * CTS + dh] = (h16)((av.x + av.y) * inv);
  };

  // D4: gates for rows G*4..G*4+3; writes prev_h to cath[CA^1]; out partials (dbuf by p&1).
  auto D4g = [&](int G, int CA, float* cregG, int p) {
    const int arow = G * 4 + (ln & 3);
    f32x4 ag[3] = {{0.f,0.f,0.f,0.f},{0.f,0.f,0.f,0.f},{0.f,0.f,0.f,0.f}};
    #pragma unroll
    for (int kt = 0; kt < 8; ++kt) {
      h16x8 af = *(const h16x8*)(sh_cath + CA * 8 * CTS + arow * CTS + kt * 32 + lq * 8);
      #pragma unroll
      for (int g = 0; g < 3; ++g)
        mfma_b(ag[g], af, bfD[g][kt]);
    }
    if (lq == 0) {
      float contrib[4];
      #pragma unroll
      for (int reg = 0; reg < 4; ++reg) {
        int row = G * 4 + reg;
        float gi = sigm(ag[0][reg] + bD[0]);
        float gf = sigm(ag[1][reg] + bD[1]);
        float gg = tanh_(ag[2][reg] + bD[2]);
        float cn = gf * cregG[reg] + gi * gg;
        cregG[reg] = cn;
        sh_cath[(CA ^ 1) * 8 * CTS + row * CTS + 128 + hcol] = (h16)cn;
        contrib[reg] = cn * wcombR;
      }
      #pragma unroll
      for (int reg = 0; reg < 4; ++reg) {
        float rsum = contrib[reg];
        rsum += __shfl_xor(rsum, 1);
        rsum += __shfl_xor(rsum, 2);
        rsum += __shfl_xor(rsum, 4);
        rsum += __shfl_xor(rsum, 8);
        if (ln == 0) sh_outp[(p & 1) * 64 + w * 8 + G * 4 + reg] = rsum;
      }
    }
  };

  // ---- pipelined main loop ----
  for (int p = 0; p < NP; ++p) {
    const int CA = p & 1;

    // I1: D4(B @ p-1) || D1(A @ p)
    if (p > 0) D4g(1, (p - 1) & 1, cregB, p - 1);
    D1g(0, CA, p == 0);
    __syncthreads();

    // I2: out[p-1] finalize/flush || D1(B @ p) || D3(A @ p)
    if (p > 0 && t < DROWS) {
      float a = bconstv;
      #pragma unroll
      for (int w2 = 0; w2 < 8; ++w2) a += sh_outp[((p - 1) & 1) * 64 + w2 * 8 + t];
      int slot = (p - 1) & 7;
      sh_obuf[t * 8 + slot] = a;
      if (slot == 7) {
        int base = p - 8;
        #pragma unroll
        for (int jj = 0; jj < 8; ++jj)
          out[(size_t)(r0 + t) * NP + base + jj] = sh_obuf[t * 8 + jj];
      }
    }
    D1g(1, CA, p == 0);
    D3g(0, CA, tA, hrowA, erowA);
    __syncthreads();

    // I3: D3(B @ p) || D4(A @ p)
    D3g(1, CA, tB, hrowB, erowB);
    D4g(0, CA, cregA, p);
    __syncthreads();
  }

  // epilogue: finish B's last step, then finalize & flush out[NP-1]
  D4g(1, (NP - 1) & 1, cregB, NP - 1);
  __syncthreads();
  if (t < DROWS) {
    float a = bconstv;
    #pragma unroll
    for (int w2 = 0; w2 < 8; ++w2) a += sh_outp[((NP - 1) & 1) * 64 + w2 * 8 + t];
    sh_obuf[t * 8 + 7] = a;
    #pragma unroll
    for (int jj = 0; jj < 8; ++jj)
      out[(size_t)(r0 + t) * NP + (NP - 8) + jj] = sh_obuf[t * 8 + jj];
  }
}

extern "C" void kernel_launch(void* const* d_in, const int* in_sizes, int n_in,
                              void* d_out, int out_size, void* d_ws, size_t ws_size,
                              hipStream_t stream) {
  const float* xb      = (const float*)d_in[0];
  const float* Wih_enc = (const float*)d_in[1];
  const float* Whh_enc = (const float*)d_in[2];
  const float* bih_enc = (const float*)d_in[3];
  const float* bhh_enc = (const float*)d_in[4];
  const float* Watt    = (const float*)d_in[5];
  const float* batt    = (const float*)d_in[6];
  const float* Wih_dec = (const float*)d_in[7];
  const float* Whh_dec = (const float*)d_in[8];
  const float* bih_dec = (const float*)d_in[9];
  const float* bhh_dec = (const float*)d_in[10];
  const float* Wout    = (const float*)d_in[11];
  const float* bout    = (const float*)d_in[12];
  const float* Wfin    = (const float*)d_in[13];
  const float* bfin    = (const float*)d_in[14];
  char* ws = (char*)d_ws;  // needs ~45.6 MB

  hipFuncSetAttribute(reinterpret_cast<const void*>(fused_kernel),
                      hipFuncAttributeMaxDynamicSharedMemorySize, DSMEM);

  setup_weights<<<920, 256, 0, stream>>>(Wih_enc, Whh_enc, Wih_dec, Whh_dec,
                                         Watt, batt, Wout, bout, Wfin, bfin,
                                         bih_enc, bhh_enc, bih_dec, bhh_dec, ws);
  fused_kernel<<<NB / EROWS, NTHR, DSMEM, stream>>>(
      xb, (const h16*)(ws + WENC_OFF), (const float*)(ws + BENC_OFF),
      (unsigned int*)(ws + ENC2_OFF), (float*)(ws + HT_OFF),
      Watt, Wout, bout,
      (const h16*)(ws + WDEC_OFF), (const h16*)(ws + WEFF_OFF),
      (const float*)(ws + BEFF_OFF), (const float*)(ws + WCOMB_OFF),
      (const float*)(ws + BCONST_OFF), (const float*)(ws + BDEC_OFF),
      (float*)d_out);
}

// Round 9
// 1364.424 us; speedup vs baseline: 1.0085x; 1.0085x over previous
//
#include <hip/hip_runtime.h>
#include <hip/hip_fp8.h>

// Problem constants
#define NB   2048   // batch
#define SEQ  168    // encoder steps
#define NF   7      // features
#define NH   128    // hidden
#define NP   96     // decoder steps
#define EROWS 8     // rows/block -> 256 blocks, enc+dec fused
#define DROWS 8
#define NTHR 512
#define KE   160    // enc A/B K: [x 0..6][pad 7][h 8..135][pad 136..159]
#define KD   256    // dec A/B K: [combine 0..127][prev_h 128..255]
#define HXS  168    // h16 row stride for enc MFMA-A tile
#define CTS  264    // cath row stride in h16
#define LS4  30     // s4 groups LDS-resident (s 0..119); tail 12 s4 in registers

typedef _Float16 h16;
typedef _Float16 h16x8 __attribute__((ext_vector_type(8)));
typedef float    f32x2 __attribute__((ext_vector_type(2)));
typedef float    f32x4 __attribute__((ext_vector_type(4)));
typedef unsigned int u32x4 __attribute__((ext_vector_type(4)));

// MFMA via the compiler builtin (proved numerically correct under the pipeline in R8;
// the hand-asm variant was the R6/R7 corruption source). A/B are AV-class, so PIN_A'd
// weight fragments are consumed directly from AGPRs (unified-RF residency, no spill of
// weights). Register discipline: 2 waves/SIMD -> 256 unified regs/wave; AGPR pins use
// 112, so ALL arch-VGPR live state must stay under ~144 (R8 overflowed -> 30 MB scratch).
__device__ __forceinline__ void mfma_b(f32x4& acc, h16x8 a, h16x8 b) {
  acc = __builtin_amdgcn_mfma_f32_16x16x32_f16(a, b, acc, 0, 0, 0);
}
#define PIN_A(x) asm volatile("" : "+a"(x))

__device__ __forceinline__ float sigm(float x) { return 1.f / (1.f + __expf(-x)); }
__device__ __forceinline__ float tanh_(float x) {
  float e = __expf(-2.f * fabsf(x));
  return copysignf((1.f - e) / (1.f + e), x);
}

template <bool HI>
__device__ __forceinline__ unsigned int pack2_fp8(float a, float b, unsigned int old) {
#if __has_builtin(__builtin_amdgcn_cvt_pk_fp8_f32)
  return (unsigned int)__builtin_amdgcn_cvt_pk_fp8_f32(a, b, (int)old, HI);
#else
  __hip_fp8_e4m3 qa(a), qb(b);
  unsigned int pair = (unsigned int)(*(unsigned char*)&qa) |
                      ((unsigned int)(*(unsigned char*)&qb) << 8);
  return HI ? ((old & 0x0000ffffu) | (pair << 16)) : ((old & 0xffff0000u) | pair);
#endif
}
template <bool HI>
__device__ __forceinline__ f32x2 unp2(unsigned int w) {
#if __has_builtin(__builtin_amdgcn_cvt_pk_f32_fp8)
  return __builtin_amdgcn_cvt_pk_f32_fp8(w, HI);
#else
  __hip_fp8_e4m3 a, b;
  constexpr unsigned int sh = HI ? 16 : 0;
  *(unsigned char*)&a = (w >> sh) & 0xff;
  *(unsigned char*)&b = (w >> (sh + 8)) & 0xff;
  f32x2 r; r.x = (float)a; r.y = (float)b; return r;
#endif
}

// -------- d_ws layout (bytes). --------
constexpr size_t WENC_OFF   = 0;         // h16[512][160]
constexpr size_t WDEC_OFF   = 163840;    // h16[512][256]
constexpr size_t WEFF_OFF   = 425984;    // h16[168][128]
constexpr size_t BEFF_OFF   = 468992;    // f32[168]
constexpr size_t WCOMB_OFF  = 469760;    // f32[128]
constexpr size_t BCONST_OFF = 470272;    // f32[1]
constexpr size_t BENC_OFF   = 470528;    // f32[512]
constexpr size_t BDEC_OFF   = 472576;    // f32[512]
constexpr size_t ENC2_OFF   = 31981568;  // u32[NB][3][128][4] hist tail (s4 30..41)
constexpr size_t HT_OFF     = 44564480;  // f32[NB*NH] final encoder h

// -------- fused-kernel dynamic-LDS layout (bytes) --------
constexpr int HIST_OFF   = 0;        // u32[8][30][128]  122880
constexpr int CATH_OFF   = 122880;   // h16[2][8][CTS]     8448 -> 131328
constexpr int ATTW_OFF   = 131328;   // f32[8][168]        5376 -> 136704
constexpr int WAT2_OFF   = 136704;   // h16[40][128]      10240 -> 146944
constexpr int D0_OFF     = 146944;   // f32[8][168]        5376 -> 152320
constexpr int OUTP_OFF   = 152320;   // f32[2][8][8] dbuf   512 -> 152832
constexpr int YH_OFF     = 152832;   // f32[64]             256 -> 153088
constexpr int OBUF_OFF   = 153088;   // f32[8][8] out ring  256 -> 153344
constexpr int DSMEM      = 153344;
// enc-phase alias (dead before dec phase uses these bytes): sh_hx over CATH/ATTW
constexpr int SHHX_OFF = 122880;     // h16[2][16][HXS] = 10752 (ends 133632)

// -------- setup: cast/pack weights + algebraic folds into ws --------
__global__ void setup_weights(const float* __restrict__ Wih_enc, const float* __restrict__ Whh_enc,
                              const float* __restrict__ Wih_dec, const float* __restrict__ Whh_dec,
                              const float* __restrict__ Watt, const float* __restrict__ batt,
                              const float* __restrict__ Wout, const float* __restrict__ bout,
                              const float* __restrict__ Wfin, const float* __restrict__ bfin,
                              const float* __restrict__ bihe, const float* __restrict__ bhhe,
                              const float* __restrict__ bihd, const float* __restrict__ bhhd,
                              char* __restrict__ ws) {
  int idx = blockIdx.x * blockDim.x + threadIdx.x;
  constexpr int A0 = 81920;            // enc W
  constexpr int A1 = A0 + 131072;      // dec W
  constexpr int A2 = A1 + 21504;       // Weff
  constexpr int A3 = A2 + 168;         // beff
  constexpr int A4 = A3 + 128;         // wcomb
  constexpr int A5 = A4 + 1;           // bconst
  constexpr int A6 = A5 + 512;         // biases
  if (idx < A0) {
    int n = idx / KE, k = idx % KE;
    float v = 0.f;
    if (k < NF) v = Wih_enc[n * NF + k];
    else if (k >= 8 && k < 136) v = Whh_enc[n * NH + (k - 8)];
    ((h16*)(ws + WENC_OFF))[idx] = (h16)v;
  } else if (idx < A1) {
    int i = idx - A0;
    int n = i / KD, k = i % KD;
    float v = (k < NH) ? Wih_dec[n * NH + k] : Whh_dec[n * NH + (k - NH)];
    ((h16*)(ws + WDEC_OFF))[i] = (h16)v;
  } else if (idx < A2) {
    int i = idx - A1;
    int s = i / NH, k = i % NH;
    float v = Watt[s * (NH + NF) + k];
    #pragma unroll
    for (int f = 0; f < NF; ++f)
      v += Watt[s * (NH + NF) + NH + f] * Wout[f * NH + k];
    ((h16*)(ws + WEFF_OFF))[i] = (h16)v;
  } else if (idx < A3) {
    int s = idx - A2;
    float v = batt[s];
    #pragma unroll
    for (int f = 0; f < NF; ++f)
      v += Watt[s * (NH + NF) + NH + f] * bout[f];
    ((float*)(ws + BEFF_OFF))[s] = v;
  } else if (idx < A4) {
    int k = idx - A3;
    float v = 0.f;
    #pragma unroll
    for (int f = 0; f < NF; ++f) v += Wfin[f] * Wout[f * NH + k];
    ((float*)(ws + WCOMB_OFF))[k] = v;
  } else if (idx < A5) {
    float v = bfin[0];
    #pragma unroll
    for (int f = 0; f < NF; ++f) v += bout[f] * Wfin[f];
    ((float*)(ws + BCONST_OFF))[0] = v;
  } else if (idx < A6) {
    int g = idx - A5;
    ((float*)(ws + BENC_OFF))[g] = bihe[g] + bhhe[g];
    ((float*)(ws + BDEC_OFF))[g] = bihd[g] + bhhd[g];
  }
}

// ================= fused encoder+decoder: 8 rows/block, 256 blocks =================
// Decoder: 2-group (rows 0-3 / 4-7) software pipeline — every barrier interval holds
// one MFMA-phase and one VALU-phase from different groups:
//   I1: D4(B@p-1) | D1(A@p)     I2: D1(B@p) | D3(A@p)     I3: D3(B@p) | D4(A@p)
// Register slimming vs R8 (which spilled 30 MB): (1) cell state split by lane quad —
// lq0 lanes carry rows 0-3, lq1 rows 4-7; act condition is (lq == G); creg[4] is the
// only cell array, seeded directly from enc hstate. (2) D1g loads A-fragments per-kt
// (no afA[4] array). The 16x16 C-tile replicates the 4 group rows in every lq quad,
// so quad G holds exactly its group's outputs.
__global__ __attribute__((amdgpu_flat_work_group_size(NTHR, NTHR), amdgpu_waves_per_eu(2, 2)))
void fused_kernel(const float* __restrict__ xb, const h16* __restrict__ w16enc,
                  const float* __restrict__ bencp, unsigned int* __restrict__ encw2,
                  float* __restrict__ hTg,
                  const float* __restrict__ Watt, const float* __restrict__ Wout,
                  const float* __restrict__ bout,
                  const h16* __restrict__ w16dec, const h16* __restrict__ weff,
                  const float* __restrict__ beffp, const float* __restrict__ wcombp,
                  const float* __restrict__ bconstp, const float* __restrict__ bdecp,
                  float* __restrict__ out) {
  extern __shared__ char smem[];
  unsigned int* hist = (unsigned int*)(smem + HIST_OFF);
  h16 (*sh_hx)[16][HXS] = (h16(*)[16][HXS])(smem + SHHX_OFF);
  h16*   sh_cath  = (h16*)(smem + CATH_OFF);
  float* sh_attw  = (float*)(smem + ATTW_OFF);
  h16*   sh_watt2 = (h16*)(smem + WAT2_OFF);
  float* sh_d0    = (float*)(smem + D0_OFF);
  float* sh_outp  = (float*)(smem + OUTP_OFF);   // [2][8][8]
  float* sh_yh    = (float*)(smem + YH_OFF);
  float* sh_obuf  = (float*)(smem + OBUF_OFF);

  const int t  = threadIdx.x;
  const int r0 = blockIdx.x * EROWS;

  const int w  = t >> 6;
  const int l  = t & 63;
  const int lq = l >> 4;
  const int ln = l & 15;
  const int hcol = w * 16 + ln;
  const int mrow = lq * 4;
  const bool act = (lq < 2);   // enc: rows mrow+reg = 0..7 real

  // xstash constants (enc)
  const int j  = t & 3;
  const int rf = t >> 2;
  const int xr = rf / NF;
  const int xf = rf - xr * NF;

  // ================== ENCODER PHASE ==================
  for (int i = t; i < 2 * 16 * HXS; i += NTHR) ((h16*)sh_hx)[i] = (h16)0.f;

  h16x8 bfE[4][5];
  float bE[4];
  #pragma unroll
  for (int g = 0; g < 4; ++g) {
    int n = g * 128 + hcol;
    bE[g] = bencp[n];
    #pragma unroll
    for (int kt = 0; kt < 5; ++kt) {
      bfE[g][kt] = *(const h16x8*)(w16enc + n * KE + kt * 32 + lq * 8);
      PIN_A(bfE[g][kt]);
    }
  }
  __syncthreads();
  if (t < EROWS * NF) {
    int r = t / NF, f = t - (t / NF) * NF;
    sh_hx[0][r][f] = (h16)xb[((size_t)(r0 + r) * SEQ + 0) * NF + f];
  }

  float creg[4] = {0.f, 0.f, 0.f, 0.f};
  float hstate[4] = {0.f, 0.f, 0.f, 0.f};
  float hprev[4] = {0.f, 0.f, 0.f, 0.f};
  unsigned int hpack[4] = {0u, 0u, 0u, 0u};
  float xstash = 0.f;

  __syncthreads();

  for (int s = 0; s < SEQ; ++s) {
    const int cur = s & 1;
    if ((s & 3) == 0 && t < EROWS * NF * 4) {
      int sx = s + 1 + j;
      xstash = (sx < SEQ) ? xb[((size_t)(r0 + xr) * SEQ + sx) * NF + xf] : 0.f;
    }

    f32x4 ac[4] = {{0.f,0.f,0.f,0.f},{0.f,0.f,0.f,0.f},{0.f,0.f,0.f,0.f},{0.f,0.f,0.f,0.f}};
    #pragma unroll
    for (int kt = 0; kt < 5; ++kt) {
      h16x8 af = *(const h16x8*)(&sh_hx[cur][ln][kt * 32 + lq * 8]);
      #pragma unroll
      for (int g = 0; g < 4; ++g)
        mfma_b(ac[g], af, bfE[g][kt]);
    }

    if (act) {
      #pragma unroll
      for (int reg = 0; reg < 4; ++reg) {
        float gi = sigm(ac[0][reg] + bE[0]);
        float gf = sigm(ac[1][reg] + bE[1]);
        float gg = tanh_(ac[2][reg] + bE[2]);
        float go = sigm(ac[3][reg] + bE[3]);
        float c = gf * creg[reg] + gi * gg;
        creg[reg] = c;
        float h = go * tanh_(c);
        hstate[reg] = h;
        sh_hx[cur ^ 1][mrow + reg][8 + hcol] = (h16)h;
        float hs = h * 16.f;
        if ((s & 1) == 0) hprev[reg] = hs;
        else if ((s & 3) == 1) hpack[reg] = pack2_fp8<false>(hprev[reg], hs, hpack[reg]);
        else                   hpack[reg] = pack2_fp8<true>(hprev[reg], hs, hpack[reg]);
      }
      if ((s & 3) == 3) {
        int s4 = s >> 2;
        if (s4 < LS4) {
          #pragma unroll
          for (int reg = 0; reg < 4; ++reg)
            hist[(size_t)(mrow + reg) * (LS4 * NH) + s4 * NH + hcol] = hpack[reg];
        } else {
          int q = s4 - LS4;
          #pragma unroll
          for (int reg = 0; reg < 4; ++reg)
            encw2[(((size_t)(r0 + mrow + reg) * 3 + (q >> 2)) * NH + hcol) * 4 + (q & 3)] = hpack[reg];
        }
      }
    }
    if (t < EROWS * NF * 4 && (s & 3) == j && s + 1 < SEQ)
      sh_hx[cur ^ 1][xr][xf] = (h16)xstash;
    __syncthreads();
  }

  // h_T to global (needed cross-lane for yh init)
  if (act) {
    #pragma unroll
    for (int reg = 0; reg < 4; ++reg)
      hTg[(size_t)(r0 + mrow + reg) * NH + hcol] = hstate[reg];
  }
  __syncthreads();

  // ================== DECODER PHASE ==================
  for (int i = t; i < 40 * NH; i += NTHR) sh_watt2[i] = weff[128 * NH + i];

  h16x8 bfD[3][8];
  float bD[3];
  #pragma unroll
  for (int g = 0; g < 3; ++g) {
    int n = g * 128 + hcol;
    bD[g] = bdecp[n];
    #pragma unroll
    for (int kt = 0; kt < 8; ++kt) {
      bfD[g][kt] = *(const h16x8*)(w16dec + n * KD + kt * 32 + lq * 8);
      PIN_A(bfD[g][kt]);
    }
  }
  h16x8 bfA[4];
  #pragma unroll
  for (int kt = 0; kt < 4; ++kt) {
    bfA[kt] = *(const h16x8*)(weff + hcol * NH + kt * 32 + lq * 8);
    PIN_A(bfA[kt]);
  }
  const float beffR = beffp[hcol];
  const int s2v = 128 + hcol;
  const float beff2 = (w < 3 && s2v < SEQ) ? beffp[s2v] : 0.f;
  const float wcombR = wcombp[hcol];
  const float bconstv = bconstp[0];

  // dec cell state: creg reused — lq0 lanes carry rows 0-3 (group A), lq1 rows 4-7 (B).
  #pragma unroll
  for (int reg = 0; reg < 4; ++reg) creg[reg] = hstate[reg];
  // prev_h init into cath[0] (rows 0-7, by enc act lanes)
  if (act) {
    #pragma unroll
    for (int reg = 0; reg < 4; ++reg)
      sh_cath[0 * 8 * CTS + (mrow + reg) * CTS + 128 + hcol] = (h16)hstate[reg];
  }
  // yh[r][f] = h_T . W_out[f] + bout[f]
  if (t < DROWS * NF) {
    int r = t / NF, f = t - (t / NF) * NF;
    float a = bout[f];
    const float* wr = Wout + f * NH;
    const float* hp = hTg + (size_t)(r0 + r) * NH;
    #pragma unroll 8
    for (int k = 0; k < NH; k += 4) {
      float4 pv = *(const float4*)(hp + k);
      float4 wv = *(const float4*)(wr + k);
      a += pv.x * wv.x + pv.y * wv.y + pv.z * wv.z + pv.w * wv.w;
    }
    sh_yh[t] = a;
  }
  __syncthreads();
  // d0[r][s] = (y0[r] - yh[r]) . W_att_y[s]
  for (int i = t; i < DROWS * SEQ; i += NTHR) {
    int r = i / SEQ, s = i - (i / SEQ) * SEQ;
    float a = 0.f;
    #pragma unroll
    for (int f = 0; f < NF; ++f) {
      float y0f = xb[((size_t)(r0 + r) * SEQ + (SEQ - 1)) * NF + f];
      a += (y0f - sh_yh[r * NF + f]) * Watt[s * (NH + NF) + NH + f];
    }
    sh_d0[i] = a;
  }

  // D3 ownership: thread owns column dh for row dr of the active group
  const int dr = t >> 7;
  const int dh = t & 127;
  const unsigned int* hrowA = hist + (size_t)dr * (LS4 * NH) + dh;
  const unsigned int* hrowB = hist + (size_t)(dr + 4) * (LS4 * NH) + dh;
  const float* erowA = sh_attw + dr * SEQ;
  const float* erowB = sh_attw + (dr + 4) * SEQ;

  u32x4 tA[3], tB[3];
  {
    const u32x4* e2 = (const u32x4*)encw2;
    #pragma unroll
    for (int b = 0; b < 3; ++b) {
      tA[b] = e2[((size_t)(r0 + dr)     * 3 + b) * NH + dh];
      tB[b] = e2[((size_t)(r0 + dr + 4) * 3 + b) * NH + dh];
    }
  }
  __syncthreads();

  // ---- group-phase helpers ----
  // D1: logits for rows G*4..G*4+3. A-tile rows replicated (ln&3); act lanes lq==G.
  auto D1g = [&](int G, int CA, bool p0) {
    const h16* abase = sh_cath + CA * 8 * CTS + (G * 4 + (ln & 3)) * CTS + 128 + lq * 8;
    f32x4 acc = {0.f, 0.f, 0.f, 0.f};
    #pragma unroll
    for (int kt = 0; kt < 4; ++kt) {
      h16x8 af = *(const h16x8*)(abase + kt * 32);
      mfma_b(acc, af, bfA[kt]);
    }
    if (lq == G) {
      #pragma unroll
      for (int reg = 0; reg < 4; ++reg) {
        int row = G * 4 + reg;
        float lg = acc[reg] + beffR;
        if (p0) lg += sh_d0[row * SEQ + hcol];
        lg = fminf(fmaxf(lg, -30.f), 30.f);
        sh_attw[row * SEQ + hcol] = __expf(lg);
      }
    }
    if (w < 3) {
      int srow = (s2v < SEQ ? s2v : SEQ - 1) - 128;
      f32x4 acc2 = {0.f, 0.f, 0.f, 0.f};
      #pragma unroll
      for (int kt = 0; kt < 4; ++kt) {
        h16x8 af = *(const h16x8*)(abase + kt * 32);
        h16x8 bf2 = *(const h16x8*)(sh_watt2 + srow * NH + kt * 32 + lq * 8);
        mfma_b(acc2, af, bf2);
      }
      if (s2v < SEQ && lq == G) {
        #pragma unroll
        for (int reg = 0; reg < 4; ++reg) {
          int row = G * 4 + reg;
          float lg = acc2[reg] + beff2;
          if (p0) lg += sh_d0[row * SEQ + s2v];
          lg = fminf(fmaxf(lg, -30.f), 30.f);
          sh_attw[row * SEQ + s2v] = __expf(lg);
        }
      }
    }
  };

  // D3: combine for one group row per thread (all threads active).
  auto D3g = [&](int G, int CA, const u32x4* treg, const unsigned int* hrow, const float* erow) {
    float d = erow[l] + erow[64 + l];
    if (l < SEQ - 128) d += erow[128 + l];
    #pragma unroll
    for (int k = 1; k < 64; k <<= 1) d += __shfl_xor(d, k);
    const float inv = 0.0625f / d;

    f32x2 av = {0.f, 0.f};
    #pragma unroll 6
    for (int s4 = 0; s4 < LS4; ++s4) {
      unsigned int ev = hrow[s4 * NH];
      float4 e4 = *(const float4*)(erow + s4 * 4);
      f32x2 w01 = {e4.x, e4.y}, w23 = {e4.z, e4.w};
      av = w01 * unp2<false>(ev) + av;
      av = w23 * unp2<true>(ev) + av;
    }
    #pragma unroll
    for (int b = 0; b < 3; ++b) {
      #pragma unroll
      for (int jj = 0; jj < 4; ++jj) {
        int s4 = LS4 + b * 4 + jj;
        unsigned int ev = treg[b][jj];
        float4 e4 = *(const float4*)(erow + s4 * 4);
        f32x2 w01 = {e4.x, e4.y}, w23 = {e4.z, e4.w};
        av = w01 * unp2<false>(ev) + av;
        av = w23 * unp2<true>(ev) + av;
      }
    }
    sh_cath[CA * 8 * CTS + (G * 4 + dr) * CTS + dh] = (h16)((av.x + av.y) * inv);
  };

  // D4: gates for rows G*4..G*4+3; act lanes lq==G use their own creg; writes prev_h
  // to cath[CA^1]; out partials double-buffered by p&1.
  auto D4g = [&](int G, int CA, int p) {
    const h16* abase = sh_cath + CA * 8 * CTS + (G * 4 + (ln & 3)) * CTS + lq * 8;
    f32x4 ag[3] = {{0.f,0.f,0.f,0.f},{0.f,0.f,0.f,0.f},{0.f,0.f,0.f,0.f}};
    #pragma unroll
    for (int kt = 0; kt < 8; ++kt) {
      h16x8 af = *(const h16x8*)(abase + kt * 32);
      #pragma unroll
      for (int g = 0; g < 3; ++g)
        mfma_b(ag[g], af, bfD[g][kt]);
    }
    if (lq == G) {
      float contrib[4];
      #pragma unroll
      for (int reg = 0; reg < 4; ++reg) {
        int row = G * 4 + reg;
        float gi = sigm(ag[0][reg] + bD[0]);
        float gf = sigm(ag[1][reg] + bD[1]);
        float gg = tanh_(ag[2][reg] + bD[2]);
        float cn = gf * creg[reg] + gi * gg;
        creg[reg] = cn;
        sh_cath[(CA ^ 1) * 8 * CTS + row * CTS + 128 + hcol] = (h16)cn;
        contrib[reg] = cn * wcombR;
      }
      #pragma unroll
      for (int reg = 0; reg < 4; ++reg) {
        float rsum = contrib[reg];
        rsum += __shfl_xor(rsum, 1);
        rsum += __shfl_xor(rsum, 2);
        rsum += __shfl_xor(rsum, 4);
        rsum += __shfl_xor(rsum, 8);
        if (ln == 0) sh_outp[(p & 1) * 64 + w * 8 + G * 4 + reg] = rsum;
      }
    }
  };

  // ---- pipelined main loop ----
  for (int p = 0; p < NP; ++p) {
    const int CA = p & 1;

    // I1: D4(B @ p-1) || D1(A @ p)
    if (p > 0) D4g(1, (p - 1) & 1, p - 1);
    D1g(0, CA, p == 0);
    __syncthreads();

    // I2: out[p-1] finalize/flush || D1(B @ p) || D3(A @ p)
    if (p > 0 && t < DROWS) {
      float a = bconstv;
      #pragma unroll
      for (int w2 = 0; w2 < 8; ++w2) a += sh_outp[((p - 1) & 1) * 64 + w2 * 8 + t];
      int slot = (p - 1) & 7;
      sh_obuf[t * 8 + slot] = a;
      if (slot == 7) {
        int base = p - 8;
        #pragma unroll
        for (int jj = 0; jj < 8; ++jj)
          out[(size_t)(r0 + t) * NP + base + jj] = sh_obuf[t * 8 + jj];
      }
    }
    D1g(1, CA, p == 0);
    D3g(0, CA, tA, hrowA, erowA);
    __syncthreads();

    // I3: D3(B @ p) || D4(A @ p)
    D3g(1, CA, tB, hrowB, erowB);
    D4g(0, CA, p);
    __syncthreads();
  }

  // epilogue: finish B's last step, then finalize & flush out[NP-1]
  D4g(1, (NP - 1) & 1, NP - 1);
  __syncthreads();
  if (t < DROWS) {
    float a = bconstv;
    #pragma unroll
    for (int w2 = 0; w2 < 8; ++w2) a += sh_outp[((NP - 1) & 1) * 64 + w2 * 8 + t];
    sh_obuf[t * 8 + 7] = a;
    #pragma unroll
    for (int jj = 0; jj < 8; ++jj)
      out[(size_t)(r0 + t) * NP + (NP - 8) + jj] = sh_obuf[t * 8 + jj];
  }
}

extern "C" void kernel_launch(void* const* d_in, const int* in_sizes, int n_in,
                              void* d_out, int out_size, void* d_ws, size_t ws_size,
                              hipStream_t stream) {
  const float* xb      = (const float*)d_in[0];
  const float* Wih_enc = (const float*)d_in[1];
  const float* Whh_enc = (const float*)d_in[2];
  const float* bih_enc = (const float*)d_in[3];
  const float* bhh_enc = (const float*)d_in[4];
  const float* Watt    = (const float*)d_in[5];
  const float* batt    = (const float*)d_in[6];
  const float* Wih_dec = (const float*)d_in[7];
  const float* Whh_dec = (const float*)d_in[8];
  const float* bih_dec = (const float*)d_in[9];
  const float* bhh_dec = (const float*)d_in[10];
  const float* Wout    = (const float*)d_in[11];
  const float* bout    = (const float*)d_in[12];
  const float* Wfin    = (const float*)d_in[13];
  const float* bfin    = (const float*)d_in[14];
  char* ws = (char*)d_ws;  // needs ~45.6 MB

  hipFuncSetAttribute(reinterpret_cast<const void*>(fused_kernel),
                      hipFuncAttributeMaxDynamicSharedMemorySize, DSMEM);

  setup_weights<<<920, 256, 0, stream>>>(Wih_enc, Whh_enc, Wih_dec, Whh_dec,
                                         Watt, batt, Wout, bout, Wfin, bfin,
                                         bih_enc, bhh_enc, bih_dec, bhh_dec, ws);
  fused_kernel<<<NB / EROWS, NTHR, DSMEM, stream>>>(
      xb, (const h16*)(ws + WENC_OFF), (const float*)(ws + BENC_OFF),
      (unsigned int*)(ws + ENC2_OFF), (float*)(ws + HT_OFF),
      Watt, Wout, bout,
      (const h16*)(ws + WDEC_OFF), (const h16*)(ws + WEFF_OFF),
      (const float*)(ws + BEFF_OFF), (const float*)(ws + WCOMB_OFF),
      (const float*)(ws + BCONST_OFF), (const float*)(ws + BDEC_OFF),
      (float*)d_out);
}

// Round 10
// 1003.365 us; speedup vs baseline: 1.3714x; 1.3598x over previous
//
#include <hip/hip_runtime.h>
#include <hip/hip_fp8.h>

// Problem constants
#define NB   2048   // batch
#define SEQ  168    // encoder steps
#define NF   7      // features
#define NH   128    // hidden
#define NP   96     // decoder steps
#define EROWS 8     // rows/block -> 256 blocks, enc+dec fused
#define DROWS 8
#define NTHR 512
#define KE   160    // enc A/B K: [x 0..6][pad 7][h 8..135][pad 136..159]
#define KD   256    // dec A/B K: [combine 0..127][prev_h 128..255]
#define HXS  168    // h16 row stride for enc MFMA-A tile
#define CTS  264    // cath row stride in h16
#define LS4  30     // s4 groups LDS-resident (s 0..119); tail 12 s4 in registers

typedef _Float16 h16;
typedef _Float16 h16x8 __attribute__((ext_vector_type(8)));
typedef float    f32x2 __attribute__((ext_vector_type(2)));
typedef float    f32x4 __attribute__((ext_vector_type(4)));
typedef unsigned int u32x4 __attribute__((ext_vector_type(4)));

// MFMA with B operand sourced directly from AGPRs (gfx950 unified RF).
// This exact asm passed at 905 us in this exact (non-pipelined) structure (R5).
__device__ __forceinline__ void mfma_av(f32x4& acc, h16x8 a, const h16x8& b_agpr) {
  asm("v_mfma_f32_16x16x32_f16 %0, %1, %2, %0"
      : "+v"(acc) : "v"(a), "a"(b_agpr));
}
#define PIN_A(x) asm volatile("" : "+a"(x))

__device__ __forceinline__ float sigm(float x) { return 1.f / (1.f + __expf(-x)); }
__device__ __forceinline__ float tanh_(float x) {
  float e = __expf(-2.f * fabsf(x));
  return copysignf((1.f - e) / (1.f + e), x);
}

template <bool HI>
__device__ __forceinline__ unsigned int pack2_fp8(float a, float b, unsigned int old) {
#if __has_builtin(__builtin_amdgcn_cvt_pk_fp8_f32)
  return (unsigned int)__builtin_amdgcn_cvt_pk_fp8_f32(a, b, (int)old, HI);
#else
  __hip_fp8_e4m3 qa(a), qb(b);
  unsigned int pair = (unsigned int)(*(unsigned char*)&qa) |
                      ((unsigned int)(*(unsigned char*)&qb) << 8);
  return HI ? ((old & 0x0000ffffu) | (pair << 16)) : ((old & 0xffff0000u) | pair);
#endif
}
template <bool HI>
__device__ __forceinline__ f32x2 unp2(unsigned int w) {
#if __has_builtin(__builtin_amdgcn_cvt_pk_f32_fp8)
  return __builtin_amdgcn_cvt_pk_f32_fp8(w, HI);
#else
  __hip_fp8_e4m3 a, b;
  constexpr unsigned int sh = HI ? 16 : 0;
  *(unsigned char*)&a = (w >> sh) & 0xff;
  *(unsigned char*)&b = (w >> (sh + 8)) & 0xff;
  f32x2 r; r.x = (float)a; r.y = (float)b; return r;
#endif
}

// -------- d_ws layout (bytes). --------
constexpr size_t WENC_OFF   = 0;         // h16[512][160]
constexpr size_t WDEC_OFF   = 163840;    // h16[512][256]
constexpr size_t WEFF_OFF   = 425984;    // h16[168][128]
constexpr size_t BEFF_OFF   = 468992;    // f32[168]
constexpr size_t WCOMB_OFF  = 469760;    // f32[128]
constexpr size_t BCONST_OFF = 470272;    // f32[1]
constexpr size_t BENC_OFF   = 470528;    // f32[512]
constexpr size_t BDEC_OFF   = 472576;    // f32[512]
constexpr size_t ENC2_OFF   = 31981568;  // u32[NB][3][128][4] hist tail (s4 30..41)

// -------- fused-kernel dynamic-LDS layout (bytes) --------
constexpr int HIST_OFF   = 0;        // u32[8][30][128]  122880
constexpr int CATH_OFF   = 122880;   // h16[2][8][CTS]     8448 -> 131328
constexpr int ATTW_OFF   = 131328;   // f32[8][168]        5376 -> 136704 (also h_T staging)
constexpr int WAT2_OFF   = 136704;   // h16[40][128]      10240 -> 146944
constexpr int D0_OFF     = 146944;   // f32[8][168]        5376 -> 152320
constexpr int OUTP_OFF   = 152320;   // f32[8][8]           256 -> 152576
constexpr int YH_OFF     = 152576;   // f32[64]             256 -> 152832
constexpr int OBUF_OFF   = 152832;   // f32[8][8] out ring  256 -> 153088
constexpr int DPART_OFF  = 153088;   // f32[8][8] denom partials   -> 153344
constexpr int DPART2_OFF = 153344;   // f32[8][4] tail partials    -> 153472
constexpr int DSMEM      = 153472;
// enc-phase alias (dead before dec phase uses these bytes): sh_hx over CATH/ATTW
constexpr int SHHX_OFF = 122880;     // h16[2][16][HXS] = 10752 (ends 133632)

// -------- setup: cast/pack weights + algebraic folds into ws --------
__global__ void setup_weights(const float* __restrict__ Wih_enc, const float* __restrict__ Whh_enc,
                              const float* __restrict__ Wih_dec, const float* __restrict__ Whh_dec,
                              const float* __restrict__ Watt, const float* __restrict__ batt,
                              const float* __restrict__ Wout, const float* __restrict__ bout,
                              const float* __restrict__ Wfin, const float* __restrict__ bfin,
                              const float* __restrict__ bihe, const float* __restrict__ bhhe,
                              const float* __restrict__ bihd, const float* __restrict__ bhhd,
                              char* __restrict__ ws) {
  int idx = blockIdx.x * blockDim.x + threadIdx.x;
  constexpr int A0 = 81920;            // enc W
  constexpr int A1 = A0 + 131072;      // dec W
  constexpr int A2 = A1 + 21504;       // Weff
  constexpr int A3 = A2 + 168;         // beff
  constexpr int A4 = A3 + 128;         // wcomb
  constexpr int A5 = A4 + 1;           // bconst
  constexpr int A6 = A5 + 512;         // biases
  if (idx < A0) {
    int n = idx / KE, k = idx % KE;
    float v = 0.f;
    if (k < NF) v = Wih_enc[n * NF + k];
    else if (k >= 8 && k < 136) v = Whh_enc[n * NH + (k - 8)];
    ((h16*)(ws + WENC_OFF))[idx] = (h16)v;
  } else if (idx < A1) {
    int i = idx - A0;
    int n = i / KD, k = i % KD;
    float v = (k < NH) ? Wih_dec[n * NH + k] : Whh_dec[n * NH + (k - NH)];
    ((h16*)(ws + WDEC_OFF))[i] = (h16)v;
  } else if (idx < A2) {
    int i = idx - A1;
    int s = i / NH, k = i % NH;
    float v = Watt[s * (NH + NF) + k];
    #pragma unroll
    for (int f = 0; f < NF; ++f)
      v += Watt[s * (NH + NF) + NH + f] * Wout[f * NH + k];
    ((h16*)(ws + WEFF_OFF))[i] = (h16)v;
  } else if (idx < A3) {
    int s = idx - A2;
    float v = batt[s];
    #pragma unroll
    for (int f = 0; f < NF; ++f)
      v += Watt[s * (NH + NF) + NH + f] * bout[f];
    ((float*)(ws + BEFF_OFF))[s] = v;
  } else if (idx < A4) {
    int k = idx - A3;
    float v = 0.f;
    #pragma unroll
    for (int f = 0; f < NF; ++f) v += Wfin[f] * Wout[f * NH + k];
    ((float*)(ws + WCOMB_OFF))[k] = v;
  } else if (idx < A5) {
    float v = bfin[0];
    #pragma unroll
    for (int f = 0; f < NF; ++f) v += bout[f] * Wfin[f];
    ((float*)(ws + BCONST_OFF))[0] = v;
  } else if (idx < A6) {
    int g = idx - A5;
    ((float*)(ws + BENC_OFF))[g] = bihe[g] + bhhe[g];
    ((float*)(ws + BDEC_OFF))[g] = bihd[g] + bhhd[g];
  }
}

// ================= fused encoder+decoder: 8 rows/block, 256 blocks =================
// R5 structure (verified 905 us) + two isolated cuts:
//  (1) softmax denominators as 16-lane partials in D1 (removes D3's serial 12-shfl chain)
//  (2) h_T staged through LDS (attw region) instead of a global round-trip
__global__ __attribute__((amdgpu_flat_work_group_size(NTHR, NTHR), amdgpu_waves_per_eu(2, 2)))
void fused_kernel(const float* __restrict__ xb, const h16* __restrict__ w16enc,
                  const float* __restrict__ bencp, unsigned int* __restrict__ encw2,
                  const float* __restrict__ Watt, const float* __restrict__ Wout,
                  const float* __restrict__ bout,
                  const h16* __restrict__ w16dec, const h16* __restrict__ weff,
                  const float* __restrict__ beffp, const float* __restrict__ wcombp,
                  const float* __restrict__ bconstp, const float* __restrict__ bdecp,
                  float* __restrict__ out) {
  extern __shared__ char smem[];
  unsigned int* hist = (unsigned int*)(smem + HIST_OFF);
  h16 (*sh_hx)[16][HXS] = (h16(*)[16][HXS])(smem + SHHX_OFF);
  h16*   sh_cath  = (h16*)(smem + CATH_OFF);
  float* sh_attw  = (float*)(smem + ATTW_OFF);
  h16*   sh_watt2 = (h16*)(smem + WAT2_OFF);
  float* sh_d0    = (float*)(smem + D0_OFF);
  float* sh_outp  = (float*)(smem + OUTP_OFF);
  float* sh_yh    = (float*)(smem + YH_OFF);
  float* sh_obuf  = (float*)(smem + OBUF_OFF);
  float* sh_dp    = (float*)(smem + DPART_OFF);    // [8 rows][8 w]
  float* sh_dp2   = (float*)(smem + DPART2_OFF);   // [8 rows][4 w] (w=3 stays 0)

  const int t  = threadIdx.x;
  const int r0 = blockIdx.x * EROWS;

  const int w  = t >> 6;
  const int l  = t & 63;
  const int lq = l >> 4;
  const int ln = l & 15;
  const int hcol = w * 16 + ln;
  const int mrow = lq * 4;
  const bool act = (lq < 2);   // rows mrow+reg = 0..7 real

  // xstash constants (enc)
  const int j  = t & 3;
  const int rf = t >> 2;
  const int xr = rf / NF;
  const int xf = rf - xr * NF;

  // ================== ENCODER PHASE ==================
  for (int i = t; i < 2 * 16 * HXS; i += NTHR) ((h16*)sh_hx)[i] = (h16)0.f;

  h16x8 bfE[4][5];
  float bE[4];
  #pragma unroll
  for (int g = 0; g < 4; ++g) {
    int n = g * 128 + hcol;
    bE[g] = bencp[n];
    #pragma unroll
    for (int kt = 0; kt < 5; ++kt) {
      bfE[g][kt] = *(const h16x8*)(w16enc + n * KE + kt * 32 + lq * 8);
      PIN_A(bfE[g][kt]);
    }
  }
  __syncthreads();
  if (t < EROWS * NF) {
    int r = t / NF, f = t - (t / NF) * NF;
    sh_hx[0][r][f] = (h16)xb[((size_t)(r0 + r) * SEQ + 0) * NF + f];
  }

  float creg[4] = {0.f, 0.f, 0.f, 0.f};   // enc cell; reused as dec cell
  float hstate[4] = {0.f, 0.f, 0.f, 0.f}; // enc h -> dec prev_h/cell init
  float hprev[4] = {0.f, 0.f, 0.f, 0.f};
  unsigned int hpack[4] = {0u, 0u, 0u, 0u};
  float xstash = 0.f;

  __syncthreads();

  for (int s = 0; s < SEQ; ++s) {
    const int cur = s & 1;
    if ((s & 3) == 0 && t < EROWS * NF * 4) {
      int sx = s + 1 + j;
      xstash = (sx < SEQ) ? xb[((size_t)(r0 + xr) * SEQ + sx) * NF + xf] : 0.f;
    }

    f32x4 ac[4] = {{0.f,0.f,0.f,0.f},{0.f,0.f,0.f,0.f},{0.f,0.f,0.f,0.f},{0.f,0.f,0.f,0.f}};
    #pragma unroll
    for (int kt = 0; kt < 5; ++kt) {
      h16x8 af = *(const h16x8*)(&sh_hx[cur][ln][kt * 32 + lq * 8]);
      #pragma unroll
      for (int g = 0; g < 4; ++g)
        mfma_av(ac[g], af, bfE[g][kt]);
    }

    if (act) {
      #pragma unroll
      for (int reg = 0; reg < 4; ++reg) {
        float gi = sigm(ac[0][reg] + bE[0]);
        float gf = sigm(ac[1][reg] + bE[1]);
        float gg = tanh_(ac[2][reg] + bE[2]);
        float go = sigm(ac[3][reg] + bE[3]);
        float c = gf * creg[reg] + gi * gg;
        creg[reg] = c;
        float h = go * tanh_(c);
        hstate[reg] = h;
        sh_hx[cur ^ 1][mrow + reg][8 + hcol] = (h16)h;
        float hs = h * 16.f;
        if ((s & 1) == 0) hprev[reg] = hs;
        else if ((s & 3) == 1) hpack[reg] = pack2_fp8<false>(hprev[reg], hs, hpack[reg]);
        else                   hpack[reg] = pack2_fp8<true>(hprev[reg], hs, hpack[reg]);
      }
      if ((s & 3) == 3) {
        int s4 = s >> 2;
        if (s4 < LS4) {
          #pragma unroll
          for (int reg = 0; reg < 4; ++reg)
            hist[(size_t)(mrow + reg) * (LS4 * NH) + s4 * NH + hcol] = hpack[reg];
        } else {
          int q = s4 - LS4;
          #pragma unroll
          for (int reg = 0; reg < 4; ++reg)
            encw2[(((size_t)(r0 + mrow + reg) * 3 + (q >> 2)) * NH + hcol) * 4 + (q & 3)] = hpack[reg];
        }
      }
    }
    if (t < EROWS * NF * 4 && (s & 3) == j && s + 1 < SEQ)
      sh_hx[cur ^ 1][xr][xf] = (h16)xstash;
    __syncthreads();
  }

  // h_T staged into LDS (attw region; sh_hx is dead) for cross-lane yh init.
  if (act) {
    #pragma unroll
    for (int reg = 0; reg < 4; ++reg)
      sh_attw[(mrow + reg) * SEQ + hcol] = hstate[reg];
  }
  __syncthreads();

  // ================== DECODER PHASE ==================
  for (int i = t; i < 40 * NH; i += NTHR) sh_watt2[i] = weff[128 * NH + i];
  if (t < 32) sh_dp2[t] = 0.f;   // zero once; w==3 column never written

  h16x8 bfD[3][8];
  float bD[3];
  #pragma unroll
  for (int g = 0; g < 3; ++g) {
    int n = g * 128 + hcol;
    bD[g] = bdecp[n];
    #pragma unroll
    for (int kt = 0; kt < 8; ++kt) {
      bfD[g][kt] = *(const h16x8*)(w16dec + n * KD + kt * 32 + lq * 8);
      PIN_A(bfD[g][kt]);
    }
  }
  h16x8 bfA[4];
  #pragma unroll
  for (int kt = 0; kt < 4; ++kt) {
    bfA[kt] = *(const h16x8*)(weff + hcol * NH + kt * 32 + lq * 8);
    PIN_A(bfA[kt]);
  }
  const float beffR = beffp[hcol];
  const int s2v = 128 + hcol;
  const float beff2 = (w < 3 && s2v < SEQ) ? beffp[s2v] : 0.f;
  const float wcombR = wcombp[hcol];
  const float bconstv = bconstp[0];

  // cell/prev_h init directly from enc registers (same lane mapping)
  if (act) {
    #pragma unroll
    for (int reg = 0; reg < 4; ++reg) {
      creg[reg] = hstate[reg];
      sh_cath[0 * 8 * CTS + (mrow + reg) * CTS + 128 + hcol] = (h16)hstate[reg];
    }
  }
  // yh[r][f] = h_T . W_out[f] + bout[f]  (h_T from LDS)
  if (t < DROWS * NF) {
    int r = t / NF, f = t - (t / NF) * NF;
    float a = bout[f];
    const float* wr = Wout + f * NH;
    const float* hp = sh_attw + r * SEQ;
    #pragma unroll 8
    for (int k = 0; k < NH; k += 4) {
      float4 pv = *(const float4*)(hp + k);
      float4 wv = *(const float4*)(wr + k);
      a += pv.x * wv.x + pv.y * wv.y + pv.z * wv.z + pv.w * wv.w;
    }
    sh_yh[t] = a;
  }
  __syncthreads();
  // d0[r][s] = (y0[r] - yh[r]) . W_att_y[s]
  for (int i = t; i < DROWS * SEQ; i += NTHR) {
    int r = i / SEQ, s = i - (i / SEQ) * SEQ;
    float a = 0.f;
    #pragma unroll
    for (int f = 0; f < NF; ++f) {
      float y0f = xb[((size_t)(r0 + r) * SEQ + (SEQ - 1)) * NF + f];
      a += (y0f - sh_yh[r * NF + f]) * Watt[s * (NH + NF) + NH + f];
    }
    sh_d0[i] = a;
  }

  // D3 ownership: thread owns column dh for rows dr and dr+4
  const int dr = t >> 7;
  const int dh = t & 127;
  const unsigned int* hrowA = hist + (size_t)dr * (LS4 * NH) + dh;
  const unsigned int* hrowB = hist + (size_t)(dr + 4) * (LS4 * NH) + dh;
  const float* erowA = sh_attw + dr * SEQ;
  const float* erowB = sh_attw + (dr + 4) * SEQ;

  // step-invariant hist tail (s4 30..41) in registers (enc wrote it above)
  u32x4 tA[3], tB[3];
  {
    const u32x4* e2 = (const u32x4*)encw2;
    #pragma unroll
    for (int b = 0; b < 3; ++b) {
      tA[b] = e2[((size_t)(r0 + dr)     * 3 + b) * NH + dh];
      tB[b] = e2[((size_t)(r0 + dr + 4) * 3 + b) * NH + dh];
    }
  }
  __syncthreads();

  for (int p = 0; p < NP; ++p) {
    const int CA = p & 1;

    // finalize previous step's output into LDS ring; flush every 8 steps
    if (p > 0 && t < DROWS) {
      float a = bconstv;
      #pragma unroll
      for (int w2 = 0; w2 < 8; ++w2) a += sh_outp[w2 * 8 + t];
      int slot = (p - 1) & 7;
      sh_obuf[t * 8 + slot] = a;
      if (slot == 7) {
        int base = p - 8;
        #pragma unroll
        for (int jj = 0; jj < 8; ++jj)
          out[(size_t)(r0 + t) * NP + base + jj] = sh_obuf[t * 8 + jj];
      }
    }

    // D1: logits = prev_h @ Weff^T + beff (+d0 at p=0); e = exp(clamped);
    //     per-row denominator partials via 16-lane reduce (hidden under 2nd MFMA block)
    {
      h16x8 afA[4];
      #pragma unroll
      for (int kt = 0; kt < 4; ++kt)
        afA[kt] = *(const h16x8*)(sh_cath + CA * 8 * CTS + (ln & 7) * CTS + 128 + kt * 32 + lq * 8);
      f32x4 acc = {0.f, 0.f, 0.f, 0.f};
      #pragma unroll
      for (int kt = 0; kt < 4; ++kt)
        mfma_av(acc, afA[kt], bfA[kt]);
      if (act) {
        float ev[4];
        #pragma unroll
        for (int reg = 0; reg < 4; ++reg) {
          int row = mrow + reg;
          float lg = acc[reg] + beffR;
          if (p == 0) lg += sh_d0[row * SEQ + hcol];
          lg = fminf(fmaxf(lg, -30.f), 30.f);
          ev[reg] = __expf(lg);
          sh_attw[row * SEQ + hcol] = ev[reg];
        }
        #pragma unroll
        for (int reg = 0; reg < 4; ++reg) {
          float rs = ev[reg];
          rs += __shfl_xor(rs, 1);
          rs += __shfl_xor(rs, 2);
          rs += __shfl_xor(rs, 4);
          rs += __shfl_xor(rs, 8);
          if (ln == 0) sh_dp[(mrow + reg) * 8 + w] = rs;
        }
      }
      if (w < 3) {
        int srow = (s2v < SEQ ? s2v : SEQ - 1) - 128;
        f32x4 acc2 = {0.f, 0.f, 0.f, 0.f};
        #pragma unroll
        for (int kt = 0; kt < 4; ++kt) {
          h16x8 bf2 = *(const h16x8*)(sh_watt2 + srow * NH + kt * 32 + lq * 8);
          acc2 = __builtin_amdgcn_mfma_f32_16x16x32_f16(afA[kt], bf2, acc2, 0, 0, 0);
        }
        if (act) {
          float ev2[4];
          #pragma unroll
          for (int reg = 0; reg < 4; ++reg) {
            int row = mrow + reg;
            float e2v = 0.f;
            if (s2v < SEQ) {
              float lg = acc2[reg] + beff2;
              if (p == 0) lg += sh_d0[row * SEQ + s2v];
              lg = fminf(fmaxf(lg, -30.f), 30.f);
              e2v = __expf(lg);
              sh_attw[row * SEQ + s2v] = e2v;
            }
            ev2[reg] = e2v;
          }
          #pragma unroll
          for (int reg = 0; reg < 4; ++reg) {
            float rs = ev2[reg];
            rs += __shfl_xor(rs, 1);
            rs += __shfl_xor(rs, 2);
            rs += __shfl_xor(rs, 4);
            rs += __shfl_xor(rs, 8);
            if (ln == 0) sh_dp2[(mrow + reg) * 4 + w] = rs;
          }
        }
      }
    }
    __syncthreads();

    // D3: combine[r][h] = (sum_s e_s v_s)/(sum_s e_s); denominators from broadcast partials
    {
      float4 qa0 = *(const float4*)(sh_dp + dr * 8);
      float4 qa1 = *(const float4*)(sh_dp + dr * 8 + 4);
      float4 qa2 = *(const float4*)(sh_dp2 + dr * 4);
      float4 qb0 = *(const float4*)(sh_dp + (dr + 4) * 8);
      float4 qb1 = *(const float4*)(sh_dp + (dr + 4) * 8 + 4);
      float4 qb2 = *(const float4*)(sh_dp2 + (dr + 4) * 4);
      float dA = ((qa0.x + qa0.y) + (qa0.z + qa0.w)) + ((qa1.x + qa1.y) + (qa1.z + qa1.w))
               + ((qa2.x + qa2.y) + (qa2.z + qa2.w));
      float dB = ((qb0.x + qb0.y) + (qb0.z + qb0.w)) + ((qb1.x + qb1.y) + (qb1.z + qb1.w))
               + ((qb2.x + qb2.y) + (qb2.z + qb2.w));
      const float invA = 0.0625f / dA;
      const float invB = 0.0625f / dB;

      f32x2 avA = {0.f, 0.f};
      f32x2 avB = {0.f, 0.f};
      #pragma unroll 6
      for (int s4 = 0; s4 < LS4; ++s4) {
        unsigned int evA = hrowA[s4 * NH];
        unsigned int evB = hrowB[s4 * NH];
        float4 eA = *(const float4*)(erowA + s4 * 4);
        float4 eB = *(const float4*)(erowB + s4 * 4);
        f32x2 wA01 = {eA.x, eA.y}, wA23 = {eA.z, eA.w};
        f32x2 wB01 = {eB.x, eB.y}, wB23 = {eB.z, eB.w};
        avA = wA01 * unp2<false>(evA) + avA;
        avA = wA23 * unp2<true>(evA) + avA;
        avB = wB01 * unp2<false>(evB) + avB;
        avB = wB23 * unp2<true>(evB) + avB;
      }
      #pragma unroll
      for (int b = 0; b < 3; ++b) {
        #pragma unroll
        for (int jj = 0; jj < 4; ++jj) {
          int s4 = LS4 + b * 4 + jj;
          unsigned int evA = tA[b][jj];
          unsigned int evB = tB[b][jj];
          float4 eA = *(const float4*)(erowA + s4 * 4);
          float4 eB = *(const float4*)(erowB + s4 * 4);
          f32x2 wA01 = {eA.x, eA.y}, wA23 = {eA.z, eA.w};
          f32x2 wB01 = {eB.x, eB.y}, wB23 = {eB.z, eB.w};
          avA = wA01 * unp2<false>(evA) + avA;
          avA = wA23 * unp2<true>(evA) + avA;
          avB = wB01 * unp2<false>(evB) + avB;
          avB = wB23 * unp2<true>(evB) + avB;
        }
      }
      sh_cath[CA * 8 * CTS + dr * CTS + dh]       = (h16)((avA.x + avA.y) * invA);
      sh_cath[CA * 8 * CTS + (dr + 4) * CTS + dh] = (h16)((avB.x + avB.y) * invB);
    }
    __syncthreads();

    // D4: gates via MFMA (i,f,g) with AGPR-resident B; cell in-register; out partials
    {
      f32x4 ag[3] = {{0.f,0.f,0.f,0.f},{0.f,0.f,0.f,0.f},{0.f,0.f,0.f,0.f}};
      #pragma unroll
      for (int kt = 0; kt < 8; ++kt) {
        h16x8 af = *(const h16x8*)(sh_cath + CA * 8 * CTS + (ln & 7) * CTS + kt * 32 + lq * 8);
        #pragma unroll
        for (int g = 0; g < 3; ++g)
          mfma_av(ag[g], af, bfD[g][kt]);
      }
      if (act) {
        float contrib[4];
        #pragma unroll
        for (int reg = 0; reg < 4; ++reg) {
          int row = mrow + reg;
          float gi = sigm(ag[0][reg] + bD[0]);
          float gf = sigm(ag[1][reg] + bD[1]);
          float gg = tanh_(ag[2][reg] + bD[2]);
          float cn = gf * creg[reg] + gi * gg;
          creg[reg] = cn;
          sh_cath[(CA ^ 1) * 8 * CTS + row * CTS + 128 + hcol] = (h16)cn;
          contrib[reg] = cn * wcombR;
        }
        #pragma unroll
        for (int reg = 0; reg < 4; ++reg) {
          float rsum = contrib[reg];
          rsum += __shfl_xor(rsum, 1);
          rsum += __shfl_xor(rsum, 2);
          rsum += __shfl_xor(rsum, 4);
          rsum += __shfl_xor(rsum, 8);
          if (ln == 0) sh_outp[w * 8 + mrow + reg] = rsum;
        }
      }
    }
    __syncthreads();
  }

  // finalize last output and flush final 8 steps
  if (t < DROWS) {
    float a = bconstv;
    #pragma unroll
    for (int w2 = 0; w2 < 8; ++w2) a += sh_outp[w2 * 8 + t];
    sh_obuf[t * 8 + 7] = a;
    #pragma unroll
    for (int jj = 0; jj < 8; ++jj)
      out[(size_t)(r0 + t) * NP + (NP - 8) + jj] = sh_obuf[t * 8 + jj];
  }
}

extern "C" void kernel_launch(void* const* d_in, const int* in_sizes, int n_in,
                              void* d_out, int out_size, void* d_ws, size_t ws_size,
                              hipStream_t stream) {
  const float* xb      = (const float*)d_in[0];
  const float* Wih_enc = (const float*)d_in[1];
  const float* Whh_enc = (const float*)d_in[2];
  const float* bih_enc = (const float*)d_in[3];
  const float* bhh_enc = (const float*)d_in[4];
  const float* Watt    = (const float*)d_in[5];
  const float* batt    = (const float*)d_in[6];
  const float* Wih_dec = (const float*)d_in[7];
  const float* Whh_dec = (const float*)d_in[8];
  const float* bih_dec = (const float*)d_in[9];
  const float* bhh_dec = (const float*)d_in[10];
  const float* Wout    = (const float*)d_in[11];
  const float* bout    = (const float*)d_in[12];
  const float* Wfin    = (const float*)d_in[13];
  const float* bfin    = (const float*)d_in[14];
  char* ws = (char*)d_ws;  // needs ~45.6 MB

  hipFuncSetAttribute(reinterpret_cast<const void*>(fused_kernel),
                      hipFuncAttributeMaxDynamicSharedMemorySize, DSMEM);

  setup_weights<<<920, 256, 0, stream>>>(Wih_enc, Whh_enc, Wih_dec, Whh_dec,
                                         Watt, batt, Wout, bout, Wfin, bfin,
                                         bih_enc, bhh_enc, bih_dec, bhh_dec, ws);
  fused_kernel<<<NB / EROWS, NTHR, DSMEM, stream>>>(
      xb, (const h16*)(ws + WENC_OFF), (const float*)(ws + BENC_OFF),
      (unsigned int*)(ws + ENC2_OFF),
      Watt, Wout, bout,
      (const h16*)(ws + WDEC_OFF), (const h16*)(ws + WEFF_OFF),
      (const float*)(ws + BEFF_OFF), (const float*)(ws + WCOMB_OFF),
      (const float*)(ws + BCONST_OFF), (const float*)(ws + BDEC_OFF),
      (float*)d_out);
}

// Round 11
// 901.807 us; speedup vs baseline: 1.5258x; 1.1126x over previous
//
#include <hip/hip_runtime.h>
#include <hip/hip_fp8.h>

// Problem constants
#define NB   2048   // batch
#define SEQ  168    // encoder steps
#define NF   7      // features
#define NH   128    // hidden
#define NP   96     // decoder steps
#define EROWS 8     // rows/block -> 256 blocks, enc+dec fused
#define DROWS 8
#define NTHR 512
#define KE   160    // enc A/B K: [x 0..6][pad 7][h 8..135][pad 136..159]
#define KD   256    // dec A/B K: [combine 0..127][prev_h 128..255]
#define HXS  168    // h16 row stride for enc MFMA-A tile
#define CTS  264    // cath row stride in h16
#define LS4  30     // s4 groups LDS-resident (s 0..119); tail 12 s4 in registers

typedef _Float16 h16;
typedef _Float16 h16x8 __attribute__((ext_vector_type(8)));
typedef float    f32x2 __attribute__((ext_vector_type(2)));
typedef float    f32x4 __attribute__((ext_vector_type(4)));
typedef unsigned int u32x4 __attribute__((ext_vector_type(4)));

// MFMA with B operand sourced directly from AGPRs (gfx950 unified RF).
// This exact asm passed at 905 us in this exact (non-pipelined) structure (R5).
__device__ __forceinline__ void mfma_av(f32x4& acc, h16x8 a, const h16x8& b_agpr) {
  asm("v_mfma_f32_16x16x32_f16 %0, %1, %2, %0"
      : "+v"(acc) : "v"(a), "a"(b_agpr));
}
#define PIN_A(x) asm volatile("" : "+a"(x))

__device__ __forceinline__ float sigm(float x) { return 1.f / (1.f + __expf(-x)); }
__device__ __forceinline__ float tanh_(float x) {
  float e = __expf(-2.f * fabsf(x));
  return copysignf((1.f - e) / (1.f + e), x);
}

template <bool HI>
__device__ __forceinline__ unsigned int pack2_fp8(float a, float b, unsigned int old) {
#if __has_builtin(__builtin_amdgcn_cvt_pk_fp8_f32)
  return (unsigned int)__builtin_amdgcn_cvt_pk_fp8_f32(a, b, (int)old, HI);
#else
  __hip_fp8_e4m3 qa(a), qb(b);
  unsigned int pair = (unsigned int)(*(unsigned char*)&qa) |
                      ((unsigned int)(*(unsigned char*)&qb) << 8);
  return HI ? ((old & 0x0000ffffu) | (pair << 16)) : ((old & 0xffff0000u) | pair);
#endif
}
template <bool HI>
__device__ __forceinline__ f32x2 unp2(unsigned int w) {
#if __has_builtin(__builtin_amdgcn_cvt_pk_f32_fp8)
  return __builtin_amdgcn_cvt_pk_f32_fp8(w, HI);
#else
  __hip_fp8_e4m3 a, b;
  constexpr unsigned int sh = HI ? 16 : 0;
  *(unsigned char*)&a = (w >> sh) & 0xff;
  *(unsigned char*)&b = (w >> (sh + 8)) & 0xff;
  f32x2 r; r.x = (float)a; r.y = (float)b; return r;
#endif
}

// -------- d_ws layout (bytes). --------
constexpr size_t WENC_OFF   = 0;         // h16[512][160]
constexpr size_t WDEC_OFF   = 163840;    // h16[512][256]
constexpr size_t WEFF_OFF   = 425984;    // h16[168][128]
constexpr size_t BEFF_OFF   = 468992;    // f32[168]
constexpr size_t WCOMB_OFF  = 469760;    // f32[128]
constexpr size_t BCONST_OFF = 470272;    // f32[1]
constexpr size_t BENC_OFF   = 470528;    // f32[512]
constexpr size_t BDEC_OFF   = 472576;    // f32[512]
constexpr size_t ENC2_OFF   = 31981568;  // u32[NB][3][128][4] hist tail (s4 30..41)

// -------- fused-kernel dynamic-LDS layout (bytes) --------
constexpr int HIST_OFF   = 0;        // u32[8][30][128]  122880
constexpr int CATH_OFF   = 122880;   // h16[2][8][CTS]     8448 -> 131328
constexpr int ATTW_OFF   = 131328;   // f32[8][168]        5376 -> 136704 (also h_T staging)
constexpr int WAT2_OFF   = 136704;   // h16[40][128]      10240 -> 146944
constexpr int D0_OFF     = 146944;   // f32[8][168]        5376 -> 152320
constexpr int OUTP_OFF   = 152320;   // f32[8][8]           256 -> 152576
constexpr int YH_OFF     = 152576;   // f32[64]             256 -> 152832
constexpr int OBUF_OFF   = 152832;   // f32[8][8] out ring  256 -> 153088
constexpr int DSMEM      = 153088;
// enc-phase alias (dead before dec phase uses these bytes): sh_hx over CATH/ATTW
constexpr int SHHX_OFF = 122880;     // h16[2][16][HXS] = 10752 (ends 133632)

// -------- setup: cast/pack weights + algebraic folds into ws --------
__global__ void setup_weights(const float* __restrict__ Wih_enc, const float* __restrict__ Whh_enc,
                              const float* __restrict__ Wih_dec, const float* __restrict__ Whh_dec,
                              const float* __restrict__ Watt, const float* __restrict__ batt,
                              const float* __restrict__ Wout, const float* __restrict__ bout,
                              const float* __restrict__ Wfin, const float* __restrict__ bfin,
                              const float* __restrict__ bihe, const float* __restrict__ bhhe,
                              const float* __restrict__ bihd, const float* __restrict__ bhhd,
                              char* __restrict__ ws) {
  int idx = blockIdx.x * blockDim.x + threadIdx.x;
  constexpr int A0 = 81920;            // enc W
  constexpr int A1 = A0 + 131072;      // dec W
  constexpr int A2 = A1 + 21504;       // Weff
  constexpr int A3 = A2 + 168;         // beff
  constexpr int A4 = A3 + 128;         // wcomb
  constexpr int A5 = A4 + 1;           // bconst
  constexpr int A6 = A5 + 512;         // biases
  if (idx < A0) {
    int n = idx / KE, k = idx % KE;
    float v = 0.f;
    if (k < NF) v = Wih_enc[n * NF + k];
    else if (k >= 8 && k < 136) v = Whh_enc[n * NH + (k - 8)];
    ((h16*)(ws + WENC_OFF))[idx] = (h16)v;
  } else if (idx < A1) {
    int i = idx - A0;
    int n = i / KD, k = i % KD;
    float v = (k < NH) ? Wih_dec[n * NH + k] : Whh_dec[n * NH + (k - NH)];
    ((h16*)(ws + WDEC_OFF))[i] = (h16)v;
  } else if (idx < A2) {
    int i = idx - A1;
    int s = i / NH, k = i % NH;
    float v = Watt[s * (NH + NF) + k];
    #pragma unroll
    for (int f = 0; f < NF; ++f)
      v += Watt[s * (NH + NF) + NH + f] * Wout[f * NH + k];
    ((h16*)(ws + WEFF_OFF))[i] = (h16)v;
  } else if (idx < A3) {
    int s = idx - A2;
    float v = batt[s];
    #pragma unroll
    for (int f = 0; f < NF; ++f)
      v += Watt[s * (NH + NF) + NH + f] * bout[f];
    ((float*)(ws + BEFF_OFF))[s] = v;
  } else if (idx < A4) {
    int k = idx - A3;
    float v = 0.f;
    #pragma unroll
    for (int f = 0; f < NF; ++f) v += Wfin[f] * Wout[f * NH + k];
    ((float*)(ws + WCOMB_OFF))[k] = v;
  } else if (idx < A5) {
    float v = bfin[0];
    #pragma unroll
    for (int f = 0; f < NF; ++f) v += bout[f] * Wfin[f];
    ((float*)(ws + BCONST_OFF))[0] = v;
  } else if (idx < A6) {
    int g = idx - A5;
    ((float*)(ws + BENC_OFF))[g] = bihe[g] + bhhe[g];
    ((float*)(ws + BDEC_OFF))[g] = bihd[g] + bhhd[g];
  }
}

// ================= fused encoder+decoder: 8 rows/block, 256 blocks =================
// R5 structure (verified 905 us) + ONE isolated change (verified-correct in R10):
// h_T staged through LDS (attw region, dead at that point) instead of a global
// round-trip. The R10 denominator-offload is REMOVED (isolated -100 us).
__global__ __attribute__((amdgpu_flat_work_group_size(NTHR, NTHR), amdgpu_waves_per_eu(2, 2)))
void fused_kernel(const float* __restrict__ xb, const h16* __restrict__ w16enc,
                  const float* __restrict__ bencp, unsigned int* __restrict__ encw2,
                  const float* __restrict__ Watt, const float* __restrict__ Wout,
                  const float* __restrict__ bout,
                  const h16* __restrict__ w16dec, const h16* __restrict__ weff,
                  const float* __restrict__ beffp, const float* __restrict__ wcombp,
                  const float* __restrict__ bconstp, const float* __restrict__ bdecp,
                  float* __restrict__ out) {
  extern __shared__ char smem[];
  unsigned int* hist = (unsigned int*)(smem + HIST_OFF);
  h16 (*sh_hx)[16][HXS] = (h16(*)[16][HXS])(smem + SHHX_OFF);
  h16*   sh_cath  = (h16*)(smem + CATH_OFF);
  float* sh_attw  = (float*)(smem + ATTW_OFF);
  h16*   sh_watt2 = (h16*)(smem + WAT2_OFF);
  float* sh_d0    = (float*)(smem + D0_OFF);
  float* sh_outp  = (float*)(smem + OUTP_OFF);
  float* sh_yh    = (float*)(smem + YH_OFF);
  float* sh_obuf  = (float*)(smem + OBUF_OFF);

  const int t  = threadIdx.x;
  const int r0 = blockIdx.x * EROWS;

  const int w  = t >> 6;
  const int l  = t & 63;
  const int lq = l >> 4;
  const int ln = l & 15;
  const int hcol = w * 16 + ln;
  const int mrow = lq * 4;
  const bool act = (lq < 2);   // rows mrow+reg = 0..7 real

  // xstash constants (enc)
  const int j  = t & 3;
  const int rf = t >> 2;
  const int xr = rf / NF;
  const int xf = rf - xr * NF;

  // ================== ENCODER PHASE ==================
  for (int i = t; i < 2 * 16 * HXS; i += NTHR) ((h16*)sh_hx)[i] = (h16)0.f;

  h16x8 bfE[4][5];
  float bE[4];
  #pragma unroll
  for (int g = 0; g < 4; ++g) {
    int n = g * 128 + hcol;
    bE[g] = bencp[n];
    #pragma unroll
    for (int kt = 0; kt < 5; ++kt) {
      bfE[g][kt] = *(const h16x8*)(w16enc + n * KE + kt * 32 + lq * 8);
      PIN_A(bfE[g][kt]);
    }
  }
  __syncthreads();
  if (t < EROWS * NF) {
    int r = t / NF, f = t - (t / NF) * NF;
    sh_hx[0][r][f] = (h16)xb[((size_t)(r0 + r) * SEQ + 0) * NF + f];
  }

  float creg[4] = {0.f, 0.f, 0.f, 0.f};   // enc cell; reused as dec cell
  float hstate[4] = {0.f, 0.f, 0.f, 0.f}; // enc h -> dec prev_h/cell init
  float hprev[4] = {0.f, 0.f, 0.f, 0.f};
  unsigned int hpack[4] = {0u, 0u, 0u, 0u};
  float xstash = 0.f;

  __syncthreads();

  for (int s = 0; s < SEQ; ++s) {
    const int cur = s & 1;
    if ((s & 3) == 0 && t < EROWS * NF * 4) {
      int sx = s + 1 + j;
      xstash = (sx < SEQ) ? xb[((size_t)(r0 + xr) * SEQ + sx) * NF + xf] : 0.f;
    }

    f32x4 ac[4] = {{0.f,0.f,0.f,0.f},{0.f,0.f,0.f,0.f},{0.f,0.f,0.f,0.f},{0.f,0.f,0.f,0.f}};
    #pragma unroll
    for (int kt = 0; kt < 5; ++kt) {
      h16x8 af = *(const h16x8*)(&sh_hx[cur][ln][kt * 32 + lq * 8]);
      #pragma unroll
      for (int g = 0; g < 4; ++g)
        mfma_av(ac[g], af, bfE[g][kt]);
    }

    if (act) {
      #pragma unroll
      for (int reg = 0; reg < 4; ++reg) {
        float gi = sigm(ac[0][reg] + bE[0]);
        float gf = sigm(ac[1][reg] + bE[1]);
        float gg = tanh_(ac[2][reg] + bE[2]);
        float go = sigm(ac[3][reg] + bE[3]);
        float c = gf * creg[reg] + gi * gg;
        creg[reg] = c;
        float h = go * tanh_(c);
        hstate[reg] = h;
        sh_hx[cur ^ 1][mrow + reg][8 + hcol] = (h16)h;
        float hs = h * 16.f;
        if ((s & 1) == 0) hprev[reg] = hs;
        else if ((s & 3) == 1) hpack[reg] = pack2_fp8<false>(hprev[reg], hs, hpack[reg]);
        else                   hpack[reg] = pack2_fp8<true>(hprev[reg], hs, hpack[reg]);
      }
      if ((s & 3) == 3) {
        int s4 = s >> 2;
        if (s4 < LS4) {
          #pragma unroll
          for (int reg = 0; reg < 4; ++reg)
            hist[(size_t)(mrow + reg) * (LS4 * NH) + s4 * NH + hcol] = hpack[reg];
        } else {
          int q = s4 - LS4;
          #pragma unroll
          for (int reg = 0; reg < 4; ++reg)
            encw2[(((size_t)(r0 + mrow + reg) * 3 + (q >> 2)) * NH + hcol) * 4 + (q & 3)] = hpack[reg];
        }
      }
    }
    if (t < EROWS * NF * 4 && (s & 3) == j && s + 1 < SEQ)
      sh_hx[cur ^ 1][xr][xf] = (h16)xstash;
    __syncthreads();
  }

  // h_T staged into LDS (attw region; sh_hx is dead) for cross-lane yh init.
  if (act) {
    #pragma unroll
    for (int reg = 0; reg < 4; ++reg)
      sh_attw[(mrow + reg) * SEQ + hcol] = hstate[reg];
  }
  __syncthreads();

  // ================== DECODER PHASE ==================
  for (int i = t; i < 40 * NH; i += NTHR) sh_watt2[i] = weff[128 * NH + i];

  h16x8 bfD[3][8];
  float bD[3];
  #pragma unroll
  for (int g = 0; g < 3; ++g) {
    int n = g * 128 + hcol;
    bD[g] = bdecp[n];
    #pragma unroll
    for (int kt = 0; kt < 8; ++kt) {
      bfD[g][kt] = *(const h16x8*)(w16dec + n * KD + kt * 32 + lq * 8);
      PIN_A(bfD[g][kt]);
    }
  }
  h16x8 bfA[4];
  #pragma unroll
  for (int kt = 0; kt < 4; ++kt) {
    bfA[kt] = *(const h16x8*)(weff + hcol * NH + kt * 32 + lq * 8);
    PIN_A(bfA[kt]);
  }
  const float beffR = beffp[hcol];
  const int s2v = 128 + hcol;
  const float beff2 = (w < 3 && s2v < SEQ) ? beffp[s2v] : 0.f;
  const float wcombR = wcombp[hcol];
  const float bconstv = bconstp[0];

  // cell/prev_h init directly from enc registers (same lane mapping)
  if (act) {
    #pragma unroll
    for (int reg = 0; reg < 4; ++reg) {
      creg[reg] = hstate[reg];
      sh_cath[0 * 8 * CTS + (mrow + reg) * CTS + 128 + hcol] = (h16)hstate[reg];
    }
  }
  // yh[r][f] = h_T . W_out[f] + bout[f]  (h_T from LDS)
  if (t < DROWS * NF) {
    int r = t / NF, f = t - (t / NF) * NF;
    float a = bout[f];
    const float* wr = Wout + f * NH;
    const float* hp = sh_attw + r * SEQ;
    #pragma unroll 8
    for (int k = 0; k < NH; k += 4) {
      float4 pv = *(const float4*)(hp + k);
      float4 wv = *(const float4*)(wr + k);
      a += pv.x * wv.x + pv.y * wv.y + pv.z * wv.z + pv.w * wv.w;
    }
    sh_yh[t] = a;
  }
  __syncthreads();
  // d0[r][s] = (y0[r] - yh[r]) . W_att_y[s]
  for (int i = t; i < DROWS * SEQ; i += NTHR) {
    int r = i / SEQ, s = i - (i / SEQ) * SEQ;
    float a = 0.f;
    #pragma unroll
    for (int f = 0; f < NF; ++f) {
      float y0f = xb[((size_t)(r0 + r) * SEQ + (SEQ - 1)) * NF + f];
      a += (y0f - sh_yh[r * NF + f]) * Watt[s * (NH + NF) + NH + f];
    }
    sh_d0[i] = a;
  }

  // D3 ownership: thread owns column dh for rows dr and dr+4
  const int dr = t >> 7;
  const int dh = t & 127;
  const unsigned int* hrowA = hist + (size_t)dr * (LS4 * NH) + dh;
  const unsigned int* hrowB = hist + (size_t)(dr + 4) * (LS4 * NH) + dh;
  const float* erowA = sh_attw + dr * SEQ;
  const float* erowB = sh_attw + (dr + 4) * SEQ;

  // step-invariant hist tail (s4 30..41) in registers (enc wrote it above)
  u32x4 tA[3], tB[3];
  {
    const u32x4* e2 = (const u32x4*)encw2;
    #pragma unroll
    for (int b = 0; b < 3; ++b) {
      tA[b] = e2[((size_t)(r0 + dr)     * 3 + b) * NH + dh];
      tB[b] = e2[((size_t)(r0 + dr + 4) * 3 + b) * NH + dh];
    }
  }
  __syncthreads();

  for (int p = 0; p < NP; ++p) {
    const int CA = p & 1;

    // finalize previous step's output into LDS ring; flush every 8 steps
    if (p > 0 && t < DROWS) {
      float a = bconstv;
      #pragma unroll
      for (int w2 = 0; w2 < 8; ++w2) a += sh_outp[w2 * 8 + t];
      int slot = (p - 1) & 7;
      sh_obuf[t * 8 + slot] = a;
      if (slot == 7) {
        int base = p - 8;
        #pragma unroll
        for (int jj = 0; jj < 8; ++jj)
          out[(size_t)(r0 + t) * NP + base + jj] = sh_obuf[t * 8 + jj];
      }
    }

    // D1: logits = prev_h @ Weff^T + beff (+d0 at p=0); e = exp(clamped)
    {
      h16x8 afA[4];
      #pragma unroll
      for (int kt = 0; kt < 4; ++kt)
        afA[kt] = *(const h16x8*)(sh_cath + CA * 8 * CTS + (ln & 7) * CTS + 128 + kt * 32 + lq * 8);
      f32x4 acc = {0.f, 0.f, 0.f, 0.f};
      #pragma unroll
      for (int kt = 0; kt < 4; ++kt)
        mfma_av(acc, afA[kt], bfA[kt]);
      if (act) {
        #pragma unroll
        for (int reg = 0; reg < 4; ++reg) {
          int row = mrow + reg;
          float lg = acc[reg] + beffR;
          if (p == 0) lg += sh_d0[row * SEQ + hcol];
          lg = fminf(fmaxf(lg, -30.f), 30.f);
          sh_attw[row * SEQ + hcol] = __expf(lg);
        }
      }
      if (w < 3) {
        int srow = (s2v < SEQ ? s2v : SEQ - 1) - 128;
        f32x4 acc2 = {0.f, 0.f, 0.f, 0.f};
        #pragma unroll
        for (int kt = 0; kt < 4; ++kt) {
          h16x8 bf2 = *(const h16x8*)(sh_watt2 + srow * NH + kt * 32 + lq * 8);
          acc2 = __builtin_amdgcn_mfma_f32_16x16x32_f16(afA[kt], bf2, acc2, 0, 0, 0);
        }
        if (s2v < SEQ && act) {
          #pragma unroll
          for (int reg = 0; reg < 4; ++reg) {
            int row = mrow + reg;
            float lg = acc2[reg] + beff2;
            if (p == 0) lg += sh_d0[row * SEQ + s2v];
            lg = fminf(fmaxf(lg, -30.f), 30.f);
            sh_attw[row * SEQ + s2v] = __expf(lg);
          }
        }
      }
    }
    __syncthreads();

    // D3: combine[r][h] = (sum_s e_s v_s)/(sum_s e_s); thread owns (dh) x rows {dr, dr+4}
    {
      float dA = erowA[l] + erowA[64 + l];
      float dB = erowB[l] + erowB[64 + l];
      if (l < SEQ - 128) { dA += erowA[128 + l]; dB += erowB[128 + l]; }
      #pragma unroll
      for (int k = 1; k < 64; k <<= 1) {
        dA += __shfl_xor(dA, k);
        dB += __shfl_xor(dB, k);
      }
      const float invA = 0.0625f / dA;
      const float invB = 0.0625f / dB;

      f32x2 avA = {0.f, 0.f};
      f32x2 avB = {0.f, 0.f};
      #pragma unroll 6
      for (int s4 = 0; s4 < LS4; ++s4) {
        unsigned int evA = hrowA[s4 * NH];
        unsigned int evB = hrowB[s4 * NH];
        float4 eA = *(const float4*)(erowA + s4 * 4);
        float4 eB = *(const float4*)(erowB + s4 * 4);
        f32x2 wA01 = {eA.x, eA.y}, wA23 = {eA.z, eA.w};
        f32x2 wB01 = {eB.x, eB.y}, wB23 = {eB.z, eB.w};
        avA = wA01 * unp2<false>(evA) + avA;
        avA = wA23 * unp2<true>(evA) + avA;
        avB = wB01 * unp2<false>(evB) + avB;
        avB = wB23 * unp2<true>(evB) + avB;
      }
      #pragma unroll
      for (int b = 0; b < 3; ++b) {
        #pragma unroll
        for (int jj = 0; jj < 4; ++jj) {
          int s4 = LS4 + b * 4 + jj;
          unsigned int evA = tA[b][jj];
          unsigned int evB = tB[b][jj];
          float4 eA = *(const float4*)(erowA + s4 * 4);
          float4 eB = *(const float4*)(erowB + s4 * 4);
          f32x2 wA01 = {eA.x, eA.y}, wA23 = {eA.z, eA.w};
          f32x2 wB01 = {eB.x, eB.y}, wB23 = {eB.z, eB.w};
          avA = wA01 * unp2<false>(evA) + avA;
          avA = wA23 * unp2<true>(evA) + avA;
          avB = wB01 * unp2<false>(evB) + avB;
          avB = wB23 * unp2<true>(evB) + avB;
        }
      }
      sh_cath[CA * 8 * CTS + dr * CTS + dh]       = (h16)((avA.x + avA.y) * invA);
      sh_cath[CA * 8 * CTS + (dr + 4) * CTS + dh] = (h16)((avB.x + avB.y) * invB);
    }
    __syncthreads();

    // D4: gates via MFMA (i,f,g) with AGPR-resident B; cell in-register; out partials
    {
      f32x4 ag[3] = {{0.f,0.f,0.f,0.f},{0.f,0.f,0.f,0.f},{0.f,0.f,0.f,0.f}};
      #pragma unroll
      for (int kt = 0; kt < 8; ++kt) {
        h16x8 af = *(const h16x8*)(sh_cath + CA * 8 * CTS + (ln & 7) * CTS + kt * 32 + lq * 8);
        #pragma unroll
        for (int g = 0; g < 3; ++g)
          mfma_av(ag[g], af, bfD[g][kt]);
      }
      if (act) {
        float contrib[4];
        #pragma unroll
        for (int reg = 0; reg < 4; ++reg) {
          int row = mrow + reg;
          float gi = sigm(ag[0][reg] + bD[0]);
          float gf = sigm(ag[1][reg] + bD[1]);
          float gg = tanh_(ag[2][reg] + bD[2]);
          float cn = gf * creg[reg] + gi * gg;
          creg[reg] = cn;
          sh_cath[(CA ^ 1) * 8 * CTS + row * CTS + 128 + hcol] = (h16)cn;
          contrib[reg] = cn * wcombR;
        }
        #pragma unroll
        for (int reg = 0; reg < 4; ++reg) {
          float rsum = contrib[reg];
          rsum += __shfl_xor(rsum, 1);
          rsum += __shfl_xor(rsum, 2);
          rsum += __shfl_xor(rsum, 4);
          rsum += __shfl_xor(rsum, 8);
          if (ln == 0) sh_outp[w * 8 + mrow + reg] = rsum;
        }
      }
    }
    __syncthreads();
  }

  // finalize last output and flush final 8 steps
  if (t < DROWS) {
    float a = bconstv;
    #pragma unroll
    for (int w2 = 0; w2 < 8; ++w2) a += sh_outp[w2 * 8 + t];
    sh_obuf[t * 8 + 7] = a;
    #pragma unroll
    for (int jj = 0; jj < 8; ++jj)
      out[(size_t)(r0 + t) * NP + (NP - 8) + jj] = sh_obuf[t * 8 + jj];
  }
}

extern "C" void kernel_launch(void* const* d_in, const int* in_sizes, int n_in,
                              void* d_out, int out_size, void* d_ws, size_t ws_size,
                              hipStream_t stream) {
  const float* xb      = (const float*)d_in[0];
  const float* Wih_enc = (const float*)d_in[1];
  const float* Whh_enc = (const float*)d_in[2];
  const float* bih_enc = (const float*)d_in[3];
  const float* bhh_enc = (const float*)d_in[4];
  const float* Watt    = (const float*)d_in[5];
  const float* batt    = (const float*)d_in[6];
  const float* Wih_dec = (const float*)d_in[7];
  const float* Whh_dec = (const float*)d_in[8];
  const float* bih_dec = (const float*)d_in[9];
  const float* bhh_dec = (const float*)d_in[10];
  const float* Wout    = (const float*)d_in[11];
  const float* bout    = (const float*)d_in[12];
  const float* Wfin    = (const float*)d_in[13];
  const float* bfin    = (const float*)d_in[14];
  char* ws = (char*)d_ws;  // needs ~45.6 MB

  hipFuncSetAttribute(reinterpret_cast<const void*>(fused_kernel),
                      hipFuncAttributeMaxDynamicSharedMemorySize, DSMEM);

  setup_weights<<<920, 256, 0, stream>>>(Wih_enc, Whh_enc, Wih_dec, Whh_dec,
                                         Watt, batt, Wout, bout, Wfin, bfin,
                                         bih_enc, bhh_enc, bih_dec, bhh_dec, ws);
  fused_kernel<<<NB / EROWS, NTHR, DSMEM, stream>>>(
      xb, (const h16*)(ws + WENC_OFF), (const float*)(ws + BENC_OFF),
      (unsigned int*)(ws + ENC2_OFF),
      Watt, Wout, bout,
      (const h16*)(ws + WDEC_OFF), (const h16*)(ws + WEFF_OFF),
      (const float*)(ws + BEFF_OFF), (const float*)(ws + WCOMB_OFF),
      (const float*)(ws + BCONST_OFF), (const float*)(ws + BDEC_OFF),
      (float*)d_out);
}